// Round 6
// baseline (316.104 us; speedup 1.0000x reference)
//
#include <hip/hip_runtime.h>
#include <cstdint>
#include <cstddef>

typedef __bf16 bhalf;
typedef __bf16 bhalf8 __attribute__((ext_vector_type(8)));
typedef __bf16 bhalf4 __attribute__((ext_vector_type(4)));
typedef float f32x4 __attribute__((ext_vector_type(4)));
typedef float f32x16 __attribute__((ext_vector_type(16)));

#define RMS_EPS 1e-6f
#define N_HEADS 16
#define N_KV 4
#define HD 128
#define DIM 2048
#define SEQ 2048
#define BATCH 2

static __device__ __forceinline__ f32x4 mfma16(bhalf8 a, bhalf8 b, f32x4 c) {
    return __builtin_amdgcn_mfma_f32_16x16x32_bf16(a, b, c, 0, 0, 0);
}
static __device__ __forceinline__ f32x16 mfma32(bhalf8 a, bhalf8 b, f32x16 c) {
    return __builtin_amdgcn_mfma_f32_32x32x16_bf16(a, b, c, 0, 0, 0);
}

// async global->LDS, 16B per lane; LDS base wave-uniform (HW adds lane*16)
static __device__ __forceinline__ void gload16(const bhalf* g, bhalf* l) {
    __builtin_amdgcn_global_load_lds((const __attribute__((address_space(1))) unsigned int*)g,
                                     (__attribute__((address_space(3))) unsigned int*)l,
                                     16, 0, 0);
}

// pack two f32 -> one u32 of 2x bf16 (lo = a, hi = b)
static __device__ __forceinline__ unsigned cvt_pk_bf16(float a, float b) {
    unsigned r;
    asm volatile("v_cvt_pk_bf16_f32 %0, %1, %2" : "=v"(r) : "v"(a), "v"(b));
    return r;
}
// swap upper 32 lanes of a with lower 32 lanes of b
static __device__ __forceinline__ void plane32_swap(unsigned& a, unsigned& b) {
    asm volatile("v_permlane32_swap_b32 %0, %1" : "+v"(a), "+v"(b));
}

// ---------------- weight convert f32 -> bf16 ----------------
__global__ __launch_bounds__(256) void cvt_w(const float* __restrict__ a,
                                             const float* __restrict__ b,
                                             bhalf* __restrict__ dst) {
    size_t i = ((size_t)blockIdx.x * 256 + threadIdx.x) * 4;
    const size_t NQ = (size_t)3072 * 2048;
    float4 v = (i < NQ) ? ((const float4*)a)[i >> 2] : ((const float4*)b)[(i - NQ) >> 2];
    bhalf4 o;
    o[0] = (bhalf)v.x; o[1] = (bhalf)v.y; o[2] = (bhalf)v.z; o[3] = (bhalf)v.w;
    *(bhalf4*)(dst + i) = o;
}

// ---------------- RMSNorm: one block per row ----------------
__global__ __launch_bounds__(256) void rmsnorm_k(const float* __restrict__ x,
                                                 const float* __restrict__ w,
                                                 bhalf* __restrict__ xn) {
    const int row = blockIdx.x;
    const int tid = threadIdx.x;
    const float4* xr = (const float4*)(x + (size_t)row * DIM);
    float4 v0 = xr[tid * 2], v1 = xr[tid * 2 + 1];
    float ss = v0.x * v0.x + v0.y * v0.y + v0.z * v0.z + v0.w * v0.w
             + v1.x * v1.x + v1.y * v1.y + v1.z * v1.z + v1.w * v1.w;
    #pragma unroll
    for (int off = 32; off; off >>= 1) ss += __shfl_xor(ss, off, 64);
    __shared__ float red[4];
    if ((tid & 63) == 0) red[tid >> 6] = ss;
    __syncthreads();
    float tot = red[0] + red[1] + red[2] + red[3];
    float scale = rsqrtf(tot * (1.0f / DIM) + RMS_EPS);
    const float4* wr = (const float4*)w;
    float4 w0 = wr[tid * 2], w1 = wr[tid * 2 + 1];
    bhalf8 o;
    o[0] = (bhalf)(v0.x * scale * w0.x); o[1] = (bhalf)(v0.y * scale * w0.y);
    o[2] = (bhalf)(v0.z * scale * w0.z); o[3] = (bhalf)(v0.w * scale * w0.w);
    o[4] = (bhalf)(v1.x * scale * w1.x); o[5] = (bhalf)(v1.y * scale * w1.y);
    o[6] = (bhalf)(v1.z * scale * w1.z); o[7] = (bhalf)(v1.w * scale * w1.w);
    *(bhalf8*)(xn + (size_t)row * DIM + tid * 8) = o;
}

// ---------------- GEMM: m201 8-phase 256x256 template, BK=64 --------------
// 8 waves (2M x 4N), per-wave 128x64 output. LDS 128KB: 2 dbuf x {A0,A1,B0,B1}
// 16KB halves (A0 = tile rows 0-127 etc; B^T rows = output cols).
// Per phase: {ds_read subtile || stage 1 half-tile -> barrier -> setprio(1)
// -> 16 MFMA -> setprio(0) -> barrier}. Phase reads: ph0: A(i0-3)+B(n0-1)=12,
// ph1: B(n2-3)=4, ph2: A(i4-7)=8, ph3: 0. Stage stream (steady state):
// T.ph0:A1(T+1) T.ph1:B0(T+1) T.ph2:B1(T+1) T.ph3:A0(T+2). Counted vmcnt
// ONLY at ph3 end (before the barrier): 2 loads in flight (this phase's own
// stage); tail -> vmcnt(0). Each wave's own vmcnt + barrier => all waves'
// staged data landed (RAW); every region's re-stage is >=1 barrier after its
// last read retired (WAR). Swizzle: 16B slot ^= (row&7) within 128B rows;
// gload_lds dest LINEAR, global source pre-swizzled with the same involution;
// reads apply it too (rule #21) -> conflict-free ds_read_b128.
template <typename OutT>
__global__ __launch_bounds__(512) void gemm8p(const bhalf* __restrict__ A,
                                              const bhalf* __restrict__ B,
                                              OutT* __restrict__ C,
                                              int N, int K) {
    extern __shared__ __align__(16) char smem[];
    const int tid = threadIdx.x;
    const int wid = tid >> 6, lane = tid & 63;
    const int quad = lane >> 4, r16 = lane & 15;
    const int wm = wid >> 2, wn = wid & 3;

    const int nx = N >> 8;
    const int cpx = (int)gridDim.x >> 3;
    const int bs = (int)blockIdx.x;
    const int bid = (bs & 7) * cpx + (bs >> 3);
    const int m0 = (bid / nx) << 8, n0 = (bid % nx) << 8;

    // stage source: per-lane global addr with pre-swizzled 16B slot
    const int srow = wid * 8 + (lane >> 3);                    // 0..63
    const int scol = ((lane & 7) ^ ((lane >> 3) & 7)) << 3;    // swizzled col
    const bhalf* Asrc = A + (size_t)(m0 + srow) * K + scol;
    const bhalf* Bsrc = B + (size_t)(n0 + srow) * K + scol;
    const size_t r64K = (size_t)64 * K;
    const size_t r128K = (size_t)128 * K;

    // ds_read offsets (swizzled): slot byte = ((ks^(x7>>2))<<6) | ((quad^(x7&3))<<4)
    const int x7 = r16 & 7;
    const int sl0 = (quad ^ (x7 & 3)) << 4;
    const int ksx = (x7 >> 2) << 6;
    const int k0 = ksx, k1 = 64 ^ ksx;
    const int aoff = (wm << 14) + (r16 << 7) + sl0;                             // region A[wm]
    const int boff = ((2 + (wn >> 1)) << 14) + ((((wn & 1) << 6) + r16) << 7) + sl0; // region B[wn>>1]

    f32x4 acc[8][4];
    #pragma unroll
    for (int i = 0; i < 8; ++i)
        #pragma unroll
        for (int j = 0; j < 4; ++j) acc[i][j] = (f32x4)0.0f;

    const int NT = K >> 6;   // 64-wide K tiles (even; >=2)
    const int H = K >> 4;    // total half-tiles = 4*NT
    int h = 8;               // prologue stages halves 0..7 (tiles 0,1)

    auto STAGE = [&](int hidx) {
        const int T = hidx >> 2, f = hidx & 3;
        const bhalf* s = ((f < 2) ? Asrc : Bsrc) + ((f & 1) ? r128K : 0) + T * 64;
        char* d = smem + ((T & 1) << 16) + (f << 14) + (wid << 10);
        gload16(s, (bhalf*)d);
        gload16(s + r64K, (bhalf*)(d + 8192));
    };

    #pragma unroll
    for (int i = 0; i < 8; ++i) STAGE(i);
    asm volatile("s_waitcnt vmcnt(8)" ::: "memory");   // tile 0 landed
    __builtin_amdgcn_s_barrier();

    bhalf8 af[4][2], bf[4][2];

    for (int t = 0; t < NT; t += 2) {
        #pragma unroll
        for (int hf = 0; hf < 2; ++hf) {
            char* const bp = smem + (hf << 16);   // tile t (+hf) buffer
            // ---- phase k=0: read A i0-3 + B n0-1 (12); MFMA q(lowM, lowN)
            #pragma unroll
            for (int i = 0; i < 4; ++i) {
                af[i][0] = *(const bhalf8*)(bp + aoff + i * 2048 + k0);
                af[i][1] = *(const bhalf8*)(bp + aoff + i * 2048 + k1);
            }
            #pragma unroll
            for (int j = 0; j < 2; ++j) {
                bf[j][0] = *(const bhalf8*)(bp + boff + j * 2048 + k0);
                bf[j][1] = *(const bhalf8*)(bp + boff + j * 2048 + k1);
            }
            if ((t > 0 || hf == 1) && h < H) STAGE(h++);
            asm volatile("s_waitcnt lgkmcnt(8)" ::: "memory");
            __builtin_amdgcn_s_barrier();
            __builtin_amdgcn_s_setprio(1);
            #pragma unroll
            for (int i = 0; i < 4; ++i)
                #pragma unroll
                for (int j = 0; j < 2; ++j) {
                    acc[i][j] = mfma16(af[i][0], bf[j][0], acc[i][j]);
                    acc[i][j] = mfma16(af[i][1], bf[j][1], acc[i][j]);
                }
            __builtin_amdgcn_s_setprio(0);
            __builtin_amdgcn_s_barrier();

            // ---- phase k=1: read B n2-3 (4); MFMA q(lowM, highN)
            #pragma unroll
            for (int j = 2; j < 4; ++j) {
                bf[j][0] = *(const bhalf8*)(bp + boff + j * 2048 + k0);
                bf[j][1] = *(const bhalf8*)(bp + boff + j * 2048 + k1);
            }
            if ((t > 0 || hf == 1) && h < H) STAGE(h++);
            __builtin_amdgcn_s_barrier();
            __builtin_amdgcn_s_setprio(1);
            #pragma unroll
            for (int i = 0; i < 4; ++i)
                #pragma unroll
                for (int j = 2; j < 4; ++j) {
                    acc[i][j] = mfma16(af[i][0], bf[j][0], acc[i][j]);
                    acc[i][j] = mfma16(af[i][1], bf[j][1], acc[i][j]);
                }
            __builtin_amdgcn_s_setprio(0);
            __builtin_amdgcn_s_barrier();

            // ---- phase k=2: read A i4-7 (8); MFMA q(highM, lowN)
            #pragma unroll
            for (int i = 0; i < 4; ++i) {
                af[i][0] = *(const bhalf8*)(bp + aoff + (i + 4) * 2048 + k0);
                af[i][1] = *(const bhalf8*)(bp + aoff + (i + 4) * 2048 + k1);
            }
            if ((t > 0 || hf == 1) && h < H) STAGE(h++);
            __builtin_amdgcn_s_barrier();
            __builtin_amdgcn_s_setprio(1);
            #pragma unroll
            for (int i = 0; i < 4; ++i)
                #pragma unroll
                for (int j = 0; j < 2; ++j) {
                    acc[i + 4][j] = mfma16(af[i][0], bf[j][0], acc[i + 4][j]);
                    acc[i + 4][j] = mfma16(af[i][1], bf[j][1], acc[i + 4][j]);
                }
            __builtin_amdgcn_s_setprio(0);
            __builtin_amdgcn_s_barrier();

            // ---- phase k=3: no reads; MFMA q(highM, highN); vmcnt checkpoint
            bool st = (h < H);
            if (st) STAGE(h++);
            __builtin_amdgcn_s_barrier();
            __builtin_amdgcn_s_setprio(1);
            #pragma unroll
            for (int i = 0; i < 4; ++i)
                #pragma unroll
                for (int j = 2; j < 4; ++j) {
                    acc[i + 4][j] = mfma16(af[i][0], bf[j][0], acc[i + 4][j]);
                    acc[i + 4][j] = mfma16(af[i][1], bf[j][1], acc[i + 4][j]);
                }
            __builtin_amdgcn_s_setprio(0);
            if (st) asm volatile("s_waitcnt vmcnt(2)" ::: "memory");
            else    asm volatile("s_waitcnt vmcnt(0)" ::: "memory");
            __builtin_amdgcn_s_barrier();
        }
    }

    #pragma unroll
    for (int i = 0; i < 8; ++i) {
        const int rbase = m0 + wm * 128 + i * 16 + quad * 4;
        #pragma unroll
        for (int rr = 0; rr < 4; ++rr) {
            OutT* crow = C + (size_t)(rbase + rr) * N + n0 + wn * 64 + r16;
            #pragma unroll
            for (int j = 0; j < 4; ++j) crow[j * 16] = (OutT)acc[i][j][rr];
        }
    }
}

// ---------------- RoPE + repack q/k (bf16 qkv in), transpose v -------------
__global__ __launch_bounds__(256) void rope_k(const bhalf* __restrict__ qkv,
                                              const float* __restrict__ freqs,
                                              bhalf* __restrict__ qb,
                                              bhalf* __restrict__ kb,
                                              bhalf* __restrict__ vt) {
    const int bs = blockIdx.x;
    const int b = bs >> 11, s = bs & 2047;
    const bhalf* row = qkv + (size_t)bs * 3072;
    const int tid = threadIdx.x;

    {
        const int h = tid >> 4, d20 = (tid & 15) * 4;
        bhalf8 e = *(const bhalf8*)(row + h * HD + d20 * 2);
        const float* fp = freqs + (size_t)s * 128 + d20 * 2;
        float4 f0 = *(const float4*)fp;
        float4 f1 = *(const float4*)(fp + 4);
        bhalf8 o;
        o[0] = (bhalf)((float)e[0] * f0.x - (float)e[1] * f0.y);
        o[1] = (bhalf)((float)e[0] * f0.y + (float)e[1] * f0.x);
        o[2] = (bhalf)((float)e[2] * f0.z - (float)e[3] * f0.w);
        o[3] = (bhalf)((float)e[2] * f0.w + (float)e[3] * f0.z);
        o[4] = (bhalf)((float)e[4] * f1.x - (float)e[5] * f1.y);
        o[5] = (bhalf)((float)e[4] * f1.y + (float)e[5] * f1.x);
        o[6] = (bhalf)((float)e[6] * f1.z - (float)e[7] * f1.w);
        o[7] = (bhalf)((float)e[6] * f1.w + (float)e[7] * f1.z);
        *(bhalf8*)(qb + ((size_t)(b * N_HEADS + h) * SEQ + s) * HD + d20 * 2) = o;
    }
    if (tid < 64) {
        const int kh = tid >> 4, d20 = (tid & 15) * 4;
        bhalf8 e = *(const bhalf8*)(row + 2048 + kh * HD + d20 * 2);
        const float* fp = freqs + (size_t)s * 128 + d20 * 2;
        float4 f0 = *(const float4*)fp;
        float4 f1 = *(const float4*)(fp + 4);
        bhalf8 o;
        o[0] = (bhalf)((float)e[0] * f0.x - (float)e[1] * f0.y);
        o[1] = (bhalf)((float)e[0] * f0.y + (float)e[1] * f0.x);
        o[2] = (bhalf)((float)e[2] * f0.z - (float)e[3] * f0.w);
        o[3] = (bhalf)((float)e[2] * f0.w + (float)e[3] * f0.z);
        o[4] = (bhalf)((float)e[4] * f1.x - (float)e[5] * f1.y);
        o[5] = (bhalf)((float)e[4] * f1.y + (float)e[5] * f1.x);
        o[6] = (bhalf)((float)e[6] * f1.z - (float)e[7] * f1.w);
        o[7] = (bhalf)((float)e[6] * f1.w + (float)e[7] * f1.z);
        *(bhalf8*)(kb + ((size_t)(b * N_KV + kh) * SEQ + s) * HD + d20 * 2) = o;
    }
    for (int e = tid; e < 512; e += 256) {
        const int kh = e >> 7, d = e & 127;
        vt[((size_t)(b * N_KV + kh) * HD + d) * SEQ + s] = row[2560 + e];
    }
}

// ---------------- Flash attention (R2-verified, unchanged) -----------------
__global__ __launch_bounds__(256, 2) void attn_k(const bhalf* __restrict__ qb,
                                                 const bhalf* __restrict__ kb,
                                                 const bhalf* __restrict__ vt,
                                                 bhalf* __restrict__ ob) {
    const int tid = threadIdx.x;
    const int wave = tid >> 6, lane = tid & 63;
    const int l31 = lane & 31, h2 = lane >> 5;
    const int qw = wave & 1, kw = wave >> 1;
    const int bid = ((blockIdx.x & 7) << 6) | ((int)blockIdx.x >> 3);
    const int pair = bid & 15;
    const int hh = (bid >> 4) & 15;
    const int b = bid >> 8;
    const int kvh = hh >> 2;

    __shared__ __align__(16) char smem[33792];
    char* const sK = smem;            // [64] rows x 256 B, swizzled
    char* const sV = smem + 16384;    // [128] rows x 128 B, swizzled
    float* const mrg = (float*)smem;  // phase-end merge buffer (aliases sK/sV)

    const bhalf* Kbase = kb + (size_t)(b * N_KV + kvh) * SEQ * HD;
    const bhalf* Vbase = vt + (size_t)(b * N_KV + kvh) * HD * SEQ;
    const float SCL2 = 0.08838834764831845f * 1.4426950408889634f;

    const int mbase = (qw * 64 + lane) * 66;
    const int kr = tid >> 4, kce = (tid & 15) * 8;
    const int vr = tid >> 3, vce = (tid & 7) * 8;
    const int kcB = kce * 2, vcB = vce * 2;
    const int Xl = (h2 << 4) ^ ((l31 & 7) << 4);

    for (int phase = 0; phase < 2; ++phase) {
        const int qt = phase ? (31 - pair) : pair;
        const int qrow = qt * 64 + qw * 32 + l31;
        const int qhi = qt * 64 + qw * 32 + 31;

        const bhalf* qbase = qb + (((size_t)(b * N_HEADS + hh) * SEQ) + qrow) * HD;
        bhalf8 qf[8];
        #pragma unroll
        for (int kk = 0; kk < 8; ++kk) {
            bhalf8 q0 = *(const bhalf8*)(qbase + kk * 16 + h2 * 8);
            #pragma unroll
            for (int e = 0; e < 8; ++e) q0[e] = (bhalf)((float)q0[e] * SCL2);
            qf[kk] = q0;
        }

        f32x16 accO[4];
        #pragma unroll
        for (int dt = 0; dt < 4; ++dt) accO[dt] = (f32x16)0.0f;
        float m_i = -1e30f, l_i = 0.0f;

        bhalf8 kreg[4], vreg[4];
        #pragma unroll
        for (int i = 0; i < 4; ++i) {
            kreg[i] = *(const bhalf8*)(Kbase + (size_t)(kr + 16 * i) * HD + kce);
            vreg[i] = *(const bhalf8*)(Vbase + (size_t)(vr + 32 * i) * SEQ + vce);
        }

        for (int kt = 0; kt <= qt; ++kt) {
            __syncthreads();
            #pragma unroll
            for (int i = 0; i < 4; ++i) {
                const int rk = kr + 16 * i;
                *(bhalf8*)(sK + rk * 256 + (kcB ^ ((rk & 7) << 4))) = kreg[i];
                const int rv = vr + 32 * i;
                *(bhalf8*)(sV + rv * 128 + (vcB ^ ((rv & 7) << 4))) = vreg[i];
            }
            __syncthreads();
            if (kt < qt) {
                const int kn = (kt + 1) * 64;
                #pragma unroll
                for (int i = 0; i < 4; ++i) {
                    kreg[i] = *(const bhalf8*)(Kbase + (size_t)(kn + kr + 16 * i) * HD + kce);
                    vreg[i] = *(const bhalf8*)(Vbase + (size_t)(vr + 32 * i) * SEQ + kn + vce);
                }
            }
            if (qhi < kt * 64 + kw * 32) continue;

            f32x16 accS = (f32x16)0.0f;
            const char* kRow = sK + (kw * 32 + l31) * 256;
            #pragma unroll
            for (int kk = 0; kk < 8; ++kk)
                accS = mfma32(*(const bhalf8*)(kRow + ((kk * 32) ^ Xl)), qf[kk], accS);

            if (kt == qt) {
                #pragma unroll
                for (int r = 0; r < 16; ++r) {
                    const int key = kt * 64 + kw * 32 + (r & 3) + 8 * (r >> 2) + 4 * h2;
                    if (key > qrow) accS[r] = -1e30f;
                }
            }

            float mx = -1e30f;
            #pragma unroll
            for (int r = 0; r < 16; ++r) mx = fmaxf(mx, accS[r]);
            mx = fmaxf(mx, __shfl_xor(mx, 32, 64));

            if (!__all(mx <= m_i + 8.0f)) {
                const float mnew = fmaxf(m_i, mx);
                const float alpha = __builtin_amdgcn_exp2f(m_i - mnew);
                m_i = mnew;
                l_i *= alpha;
                #pragma unroll
                for (int dt = 0; dt < 4; ++dt)
                    #pragma unroll
                    for (int r = 0; r < 16; ++r) accO[dt][r] *= alpha;
            }

            float p[16];
            float rs = 0.0f;
            #pragma unroll
            for (int r = 0; r < 16; ++r) {
                p[r] = __builtin_amdgcn_exp2f(accS[r] - m_i);
                rs += p[r];
            }
            rs += __shfl_xor(rs, 32, 64);
            l_i += rs;

            unsigned X0 = cvt_pk_bf16(p[0],  p[1]);
            unsigned X1 = cvt_pk_bf16(p[2],  p[3]);
            unsigned X2 = cvt_pk_bf16(p[4],  p[5]);
            unsigned X3 = cvt_pk_bf16(p[6],  p[7]);
            unsigned X4 = cvt_pk_bf16(p[8],  p[9]);
            unsigned X5 = cvt_pk_bf16(p[10], p[11]);
            unsigned X6 = cvt_pk_bf16(p[12], p[13]);
            unsigned X7 = cvt_pk_bf16(p[14], p[15]);
            plane32_swap(X0, X2);
            plane32_swap(X1, X3);
            plane32_swap(X4, X6);
            plane32_swap(X5, X7);
            union { unsigned u[8]; bhalf8 h[2]; } pk;
            pk.u[0] = X0; pk.u[1] = X1; pk.u[2] = X2; pk.u[3] = X3;
            pk.u[4] = X4; pk.u[5] = X5; pk.u[6] = X6; pk.u[7] = X7;

            #pragma unroll
            for (int kk2 = 0; kk2 < 2; ++kk2) {
                const int cb = (kw << 6) | (kk2 << 5);
                #pragma unroll
                for (int dt = 0; dt < 4; ++dt) {
                    const bhalf8 vfv = *(const bhalf8*)(sV + (dt * 32 + l31) * 128 + (cb ^ Xl));
                    accO[dt] = mfma32(vfv, pk.h[kk2], accO[dt]);
                }
            }
        }

        __syncthreads();
        if (kw == 1) {
            #pragma unroll
            for (int dt = 0; dt < 4; ++dt)
                #pragma unroll
                for (int r = 0; r < 16; ++r) mrg[mbase + dt * 16 + r] = accO[dt][r];
            mrg[mbase + 64] = m_i;
            mrg[mbase + 65] = l_i;
        }
        __syncthreads();
        if (kw == 0) {
            const float m1 = mrg[mbase + 64];
            const float l1 = mrg[mbase + 65];
            const float m = fmaxf(m_i, m1);
            const float b0 = __builtin_amdgcn_exp2f(m_i - m);
            const float b1 = __builtin_amdgcn_exp2f(m1 - m);
            const float inv = 1.0f / (l_i * b0 + l1 * b1);
            bhalf* obase = ob + ((size_t)b * SEQ + qrow) * (size_t)(N_HEADS * HD) + hh * HD;
            #pragma unroll
            for (int dt = 0; dt < 4; ++dt)
                #pragma unroll
                for (int c = 0; c < 4; ++c) {
                    bhalf4 o4;
                    #pragma unroll
                    for (int rr = 0; rr < 4; ++rr) {
                        const float v = accO[dt][c * 4 + rr] * b0 +
                                        mrg[mbase + dt * 16 + c * 4 + rr] * b1;
                        o4[rr] = (bhalf)(v * inv);
                    }
                    *(bhalf4*)(obase + dt * 32 + c * 8 + h2 * 4) = o4;
                }
        }
    }
}

extern "C" void kernel_launch(void* const* d_in, const int* in_sizes, int n_in,
                              void* d_out, int out_size, void* d_ws, size_t ws_size,
                              hipStream_t stream) {
    const float* x      = (const float*)d_in[0];
    const float* freqs  = (const float*)d_in[1];
    const float* norm_w = (const float*)d_in[2];
    const float* wqkv   = (const float*)d_in[3];
    const float* wo     = (const float*)d_in[4];
    float* out = (float*)d_out;

    char* ws = (char*)d_ws;
    bhalf* wqkv_b = (bhalf*)(ws);                      // 12,582,912
    bhalf* wo_b   = (bhalf*)(ws + 12582912);           //  8,388,608
    bhalf* xn     = (bhalf*)(ws + 20971520);           // 16,777,216
    bhalf* qkv    = (bhalf*)(ws + 37748736);           // 25,165,824 (bf16)
    bhalf* qb     = (bhalf*)(ws + 88080384);           // 16,777,216
    bhalf* kb     = (bhalf*)(ws + 104857600);          //  4,194,304
    bhalf* vtb    = (bhalf*)(ws + 109051904);          //  4,194,304
    bhalf* attn   = (bhalf*)(ws + 113246208);          // 16,777,216

    static bool attr_done = false;
    if (!attr_done) {
        hipFuncSetAttribute((const void*)gemm8p<bhalf>,
                            hipFuncAttributeMaxDynamicSharedMemorySize, 131072);
        hipFuncSetAttribute((const void*)gemm8p<float>,
                            hipFuncAttributeMaxDynamicSharedMemorySize, 131072);
        attr_done = true;
    }

    cvt_w<<<10240, 256, 0, stream>>>(wqkv, wo, wqkv_b);
    rmsnorm_k<<<BATCH * SEQ, 256, 0, stream>>>(x, norm_w, xn);
    gemm8p<bhalf><<<192, 512, 131072, stream>>>(xn, wqkv_b, qkv, 3072, 2048);
    rope_k<<<BATCH * SEQ, 256, 0, stream>>>(qkv, freqs, qb, kb, vtb);
    attn_k<<<512, 256, 0, stream>>>(qb, kb, vtb, attn);
    gemm8p<float><<<128, 512, 131072, stream>>>(attn, wo_b, out, 2048, 2048);
}

// Round 7
// 290.756 us; speedup vs baseline: 1.0872x; 1.0872x over previous
//
#include <hip/hip_runtime.h>
#include <cstdint>
#include <cstddef>

typedef __bf16 bhalf;
typedef __bf16 bhalf8 __attribute__((ext_vector_type(8)));
typedef __bf16 bhalf4 __attribute__((ext_vector_type(4)));
typedef float f32x4 __attribute__((ext_vector_type(4)));
typedef float f32x16 __attribute__((ext_vector_type(16)));

#define RMS_EPS 1e-6f
#define N_HEADS 16
#define N_KV 4
#define HD 128
#define DIM 2048
#define SEQ 2048
#define BATCH 2

static __device__ __forceinline__ f32x4 mfma16(bhalf8 a, bhalf8 b, f32x4 c) {
    return __builtin_amdgcn_mfma_f32_16x16x32_bf16(a, b, c, 0, 0, 0);
}
static __device__ __forceinline__ f32x16 mfma32(bhalf8 a, bhalf8 b, f32x16 c) {
    return __builtin_amdgcn_mfma_f32_32x32x16_bf16(a, b, c, 0, 0, 0);
}

// async global->LDS, 16B per lane; LDS base wave-uniform (HW adds lane*16)
static __device__ __forceinline__ void gload16(const bhalf* g, bhalf* l) {
    __builtin_amdgcn_global_load_lds((const __attribute__((address_space(1))) unsigned int*)g,
                                     (__attribute__((address_space(3))) unsigned int*)l,
                                     16, 0, 0);
}

// pack two f32 -> one u32 of 2x bf16 (lo = a, hi = b)
static __device__ __forceinline__ unsigned cvt_pk_bf16(float a, float b) {
    unsigned r;
    asm volatile("v_cvt_pk_bf16_f32 %0, %1, %2" : "=v"(r) : "v"(a), "v"(b));
    return r;
}
// swap upper 32 lanes of a with lower 32 lanes of b
static __device__ __forceinline__ void plane32_swap(unsigned& a, unsigned& b) {
    asm volatile("v_permlane32_swap_b32 %0, %1" : "+v"(a), "+v"(b));
}

// ---------------- weight convert f32 -> bf16 ----------------
__global__ __launch_bounds__(256) void cvt_w(const float* __restrict__ a,
                                             const float* __restrict__ b,
                                             bhalf* __restrict__ dst) {
    size_t i = ((size_t)blockIdx.x * 256 + threadIdx.x) * 4;
    const size_t NQ = (size_t)3072 * 2048;
    float4 v = (i < NQ) ? ((const float4*)a)[i >> 2] : ((const float4*)b)[(i - NQ) >> 2];
    bhalf4 o;
    o[0] = (bhalf)v.x; o[1] = (bhalf)v.y; o[2] = (bhalf)v.z; o[3] = (bhalf)v.w;
    *(bhalf4*)(dst + i) = o;
}

// ---------------- RMSNorm: one block per row ----------------
__global__ __launch_bounds__(256) void rmsnorm_k(const float* __restrict__ x,
                                                 const float* __restrict__ w,
                                                 bhalf* __restrict__ xn) {
    const int row = blockIdx.x;
    const int tid = threadIdx.x;
    const float4* xr = (const float4*)(x + (size_t)row * DIM);
    float4 v0 = xr[tid * 2], v1 = xr[tid * 2 + 1];
    float ss = v0.x * v0.x + v0.y * v0.y + v0.z * v0.z + v0.w * v0.w
             + v1.x * v1.x + v1.y * v1.y + v1.z * v1.z + v1.w * v1.w;
    #pragma unroll
    for (int off = 32; off; off >>= 1) ss += __shfl_xor(ss, off, 64);
    __shared__ float red[4];
    if ((tid & 63) == 0) red[tid >> 6] = ss;
    __syncthreads();
    float tot = red[0] + red[1] + red[2] + red[3];
    float scale = rsqrtf(tot * (1.0f / DIM) + RMS_EPS);
    const float4* wr = (const float4*)w;
    float4 w0 = wr[tid * 2], w1 = wr[tid * 2 + 1];
    bhalf8 o;
    o[0] = (bhalf)(v0.x * scale * w0.x); o[1] = (bhalf)(v0.y * scale * w0.y);
    o[2] = (bhalf)(v0.z * scale * w0.z); o[3] = (bhalf)(v0.w * scale * w0.w);
    o[4] = (bhalf)(v1.x * scale * w1.x); o[5] = (bhalf)(v1.y * scale * w1.y);
    o[6] = (bhalf)(v1.z * scale * w1.z); o[7] = (bhalf)(v1.w * scale * w1.w);
    *(bhalf8*)(xn + (size_t)row * DIM + tid * 8) = o;
}

// ---------------- GEMM: m201 8-phase 256x256 template, BK=64 (QKV) --------
// (R6-verified: bank-conflicts = 0, 67.9us on 192 blocks.)
template <typename OutT>
__global__ __launch_bounds__(512) void gemm8p(const bhalf* __restrict__ A,
                                              const bhalf* __restrict__ B,
                                              OutT* __restrict__ C,
                                              int N, int K) {
    extern __shared__ __align__(16) char smem[];
    const int tid = threadIdx.x;
    const int wid = tid >> 6, lane = tid & 63;
    const int quad = lane >> 4, r16 = lane & 15;
    const int wm = wid >> 2, wn = wid & 3;

    const int nx = N >> 8;
    const int cpx = (int)gridDim.x >> 3;
    const int bs = (int)blockIdx.x;
    const int bid = (bs & 7) * cpx + (bs >> 3);
    const int m0 = (bid / nx) << 8, n0 = (bid % nx) << 8;

    const int srow = wid * 8 + (lane >> 3);
    const int scol = ((lane & 7) ^ ((lane >> 3) & 7)) << 3;
    const bhalf* Asrc = A + (size_t)(m0 + srow) * K + scol;
    const bhalf* Bsrc = B + (size_t)(n0 + srow) * K + scol;
    const size_t r64K = (size_t)64 * K;
    const size_t r128K = (size_t)128 * K;

    const int x7 = r16 & 7;
    const int sl0 = (quad ^ (x7 & 3)) << 4;
    const int ksx = (x7 >> 2) << 6;
    const int k0 = ksx, k1 = 64 ^ ksx;
    const int aoff = (wm << 14) + (r16 << 7) + sl0;
    const int boff = ((2 + (wn >> 1)) << 14) + ((((wn & 1) << 6) + r16) << 7) + sl0;

    f32x4 acc[8][4];
    #pragma unroll
    for (int i = 0; i < 8; ++i)
        #pragma unroll
        for (int j = 0; j < 4; ++j) acc[i][j] = (f32x4)0.0f;

    const int NT = K >> 6;
    const int H = K >> 4;
    int h = 8;

    auto STAGE = [&](int hidx) {
        const int T = hidx >> 2, f = hidx & 3;
        const bhalf* s = ((f < 2) ? Asrc : Bsrc) + ((f & 1) ? r128K : 0) + T * 64;
        char* d = smem + ((T & 1) << 16) + (f << 14) + (wid << 10);
        gload16(s, (bhalf*)d);
        gload16(s + r64K, (bhalf*)(d + 8192));
    };

    #pragma unroll
    for (int i = 0; i < 8; ++i) STAGE(i);
    asm volatile("s_waitcnt vmcnt(8)" ::: "memory");
    __builtin_amdgcn_s_barrier();

    bhalf8 af[4][2], bf[4][2];

    for (int t = 0; t < NT; t += 2) {
        #pragma unroll
        for (int hf = 0; hf < 2; ++hf) {
            char* const bp = smem + (hf << 16);
            // phase 0
            #pragma unroll
            for (int i = 0; i < 4; ++i) {
                af[i][0] = *(const bhalf8*)(bp + aoff + i * 2048 + k0);
                af[i][1] = *(const bhalf8*)(bp + aoff + i * 2048 + k1);
            }
            #pragma unroll
            for (int j = 0; j < 2; ++j) {
                bf[j][0] = *(const bhalf8*)(bp + boff + j * 2048 + k0);
                bf[j][1] = *(const bhalf8*)(bp + boff + j * 2048 + k1);
            }
            if ((t > 0 || hf == 1) && h < H) STAGE(h++);
            asm volatile("s_waitcnt lgkmcnt(8)" ::: "memory");
            __builtin_amdgcn_s_barrier();
            __builtin_amdgcn_s_setprio(1);
            #pragma unroll
            for (int i = 0; i < 4; ++i)
                #pragma unroll
                for (int j = 0; j < 2; ++j) {
                    acc[i][j] = mfma16(af[i][0], bf[j][0], acc[i][j]);
                    acc[i][j] = mfma16(af[i][1], bf[j][1], acc[i][j]);
                }
            __builtin_amdgcn_s_setprio(0);
            __builtin_amdgcn_s_barrier();

            // phase 1
            #pragma unroll
            for (int j = 2; j < 4; ++j) {
                bf[j][0] = *(const bhalf8*)(bp + boff + j * 2048 + k0);
                bf[j][1] = *(const bhalf8*)(bp + boff + j * 2048 + k1);
            }
            if ((t > 0 || hf == 1) && h < H) STAGE(h++);
            __builtin_amdgcn_s_barrier();
            __builtin_amdgcn_s_setprio(1);
            #pragma unroll
            for (int i = 0; i < 4; ++i)
                #pragma unroll
                for (int j = 2; j < 4; ++j) {
                    acc[i][j] = mfma16(af[i][0], bf[j][0], acc[i][j]);
                    acc[i][j] = mfma16(af[i][1], bf[j][1], acc[i][j]);
                }
            __builtin_amdgcn_s_setprio(0);
            __builtin_amdgcn_s_barrier();

            // phase 2
            #pragma unroll
            for (int i = 0; i < 4; ++i) {
                af[i][0] = *(const bhalf8*)(bp + aoff + (i + 4) * 2048 + k0);
                af[i][1] = *(const bhalf8*)(bp + aoff + (i + 4) * 2048 + k1);
            }
            if ((t > 0 || hf == 1) && h < H) STAGE(h++);
            __builtin_amdgcn_s_barrier();
            __builtin_amdgcn_s_setprio(1);
            #pragma unroll
            for (int i = 0; i < 4; ++i)
                #pragma unroll
                for (int j = 0; j < 2; ++j) {
                    acc[i + 4][j] = mfma16(af[i][0], bf[j][0], acc[i + 4][j]);
                    acc[i + 4][j] = mfma16(af[i][1], bf[j][1], acc[i + 4][j]);
                }
            __builtin_amdgcn_s_setprio(0);
            __builtin_amdgcn_s_barrier();

            // phase 3 + vmcnt checkpoint
            bool st = (h < H);
            if (st) STAGE(h++);
            __builtin_amdgcn_s_barrier();
            __builtin_amdgcn_s_setprio(1);
            #pragma unroll
            for (int i = 0; i < 4; ++i)
                #pragma unroll
                for (int j = 2; j < 4; ++j) {
                    acc[i + 4][j] = mfma16(af[i][0], bf[j][0], acc[i + 4][j]);
                    acc[i + 4][j] = mfma16(af[i][1], bf[j][1], acc[i + 4][j]);
                }
            __builtin_amdgcn_s_setprio(0);
            if (st) asm volatile("s_waitcnt vmcnt(2)" ::: "memory");
            else    asm volatile("s_waitcnt vmcnt(0)" ::: "memory");
            __builtin_amdgcn_s_barrier();
        }
    }

    #pragma unroll
    for (int i = 0; i < 8; ++i) {
        const int rbase = m0 + wm * 128 + i * 16 + quad * 4;
        #pragma unroll
        for (int rr = 0; rr < 4; ++rr) {
            OutT* crow = C + (size_t)(rbase + rr) * N + n0 + wn * 64 + r16;
            #pragma unroll
            for (int j = 0; j < 4; ++j) crow[j * 16] = (OutT)acc[i][j][rr];
        }
    }
}

// ---------------- GEMM 128x128 (R4-verified): full-coverage WO -------------
template <typename OutT>
__global__ __launch_bounds__(256) void gemm128(const bhalf* __restrict__ A,
                                               const bhalf* __restrict__ B,
                                               OutT* __restrict__ C,
                                               int N, int K) {
    const int tid = threadIdx.x;
    const int w = tid >> 6, lane = tid & 63;
    const int quad = lane >> 4, r16 = lane & 15;
    const int wm = w >> 1, wn = w & 1;

    const int nx = N >> 7;
    const int cpx = (int)gridDim.x >> 3;
    const int bs = (int)blockIdx.x;
    const int bid = (bs & 7) * cpx + (bs >> 3);
    const int m0 = (bid / nx) << 7, n0 = (bid % nx) << 7;

    __shared__ __align__(16) char smem[49152];
    char* const sA = smem;           // 3 x 8KB, [128 rows][64B], swizzled
    char* const sB = smem + 24576;   // 3 x 8KB

    const int srow = lane >> 2;
    const int scol = ((lane & 3) ^ (srow & 3)) << 3;
    const bhalf* Ast = A + (size_t)(m0 + w * 16 + srow) * K + scol;
    const bhalf* Bst = B + (size_t)(n0 + w * 16 + srow) * K + scol;
    const size_t r64K = (size_t)64 * K;

    const int xorr = (r16 & 3) << 4;
    const int rdA = (wm * 64 + r16) * 64 + ((quad * 16) ^ xorr);
    const int rdB = (wn * 64 + r16) * 64 + ((quad * 16) ^ xorr);

    f32x4 acc[4][4];
    #pragma unroll
    for (int i = 0; i < 4; ++i)
        #pragma unroll
        for (int j = 0; j < 4; ++j) acc[i][j] = (f32x4)0.0f;

    const int NT = K >> 5;

    #define STG128(t, buf) do {                                                        \
        gload16(Ast + (size_t)(t) * 32,        (bhalf*)(sA + (buf) * 8192 + w * 1024));        \
        gload16(Ast + (size_t)(t) * 32 + r64K, (bhalf*)(sA + (buf) * 8192 + 4096 + w * 1024)); \
        gload16(Bst + (size_t)(t) * 32,        (bhalf*)(sB + (buf) * 8192 + w * 1024));        \
        gload16(Bst + (size_t)(t) * 32 + r64K, (bhalf*)(sB + (buf) * 8192 + 4096 + w * 1024)); \
    } while (0)

    STG128(0, 0);
    STG128(1, 1);

    int cur = 0, c2 = 2;
    for (int t = 0; t < NT; ++t) {
        if (t + 1 < NT) asm volatile("s_waitcnt vmcnt(4)" ::: "memory");
        else            asm volatile("s_waitcnt vmcnt(0)" ::: "memory");
        __builtin_amdgcn_s_barrier();

        char* const bufA = sA + cur * 8192;
        char* const bufB = sB + cur * 8192;
        bhalf8 af[4], bf[4];
        #pragma unroll
        for (int i = 0; i < 4; ++i) af[i] = *(const bhalf8*)(bufA + rdA + i * 1024);
        #pragma unroll
        for (int j = 0; j < 4; ++j) bf[j] = *(const bhalf8*)(bufB + rdB + j * 1024);

        if (t + 2 < NT) STG128(t + 2, c2);

        __builtin_amdgcn_s_setprio(1);
        #pragma unroll
        for (int i = 0; i < 4; ++i)
            #pragma unroll
            for (int j = 0; j < 4; ++j)
                acc[i][j] = mfma16(af[i], bf[j], acc[i][j]);
        __builtin_amdgcn_s_setprio(0);

        cur = (cur == 2) ? 0 : cur + 1;
        c2 = (c2 == 2) ? 0 : c2 + 1;
    }
    #undef STG128

    #pragma unroll
    for (int i = 0; i < 4; ++i) {
        const int rbase = m0 + wm * 64 + i * 16 + quad * 4;
        #pragma unroll
        for (int rr = 0; rr < 4; ++rr) {
            OutT* crow = C + (size_t)(rbase + rr) * N + n0 + wn * 64 + r16;
            #pragma unroll
            for (int j = 0; j < 4; ++j) crow[j * 16] = (OutT)acc[i][j][rr];
        }
    }
}

// ---------------- RoPE + repack q/k (v handled by vtrans_k) ----------------
__global__ __launch_bounds__(256) void rope_k(const bhalf* __restrict__ qkv,
                                              const float* __restrict__ freqs,
                                              bhalf* __restrict__ qb,
                                              bhalf* __restrict__ kb) {
    const int bs = blockIdx.x;
    const int b = bs >> 11, s = bs & 2047;
    const bhalf* row = qkv + (size_t)bs * 3072;
    const int tid = threadIdx.x;

    {
        const int h = tid >> 4, d20 = (tid & 15) * 4;
        bhalf8 e = *(const bhalf8*)(row + h * HD + d20 * 2);
        const float* fp = freqs + (size_t)s * 128 + d20 * 2;
        float4 f0 = *(const float4*)fp;
        float4 f1 = *(const float4*)(fp + 4);
        bhalf8 o;
        o[0] = (bhalf)((float)e[0] * f0.x - (float)e[1] * f0.y);
        o[1] = (bhalf)((float)e[0] * f0.y + (float)e[1] * f0.x);
        o[2] = (bhalf)((float)e[2] * f0.z - (float)e[3] * f0.w);
        o[3] = (bhalf)((float)e[2] * f0.w + (float)e[3] * f0.z);
        o[4] = (bhalf)((float)e[4] * f1.x - (float)e[5] * f1.y);
        o[5] = (bhalf)((float)e[4] * f1.y + (float)e[5] * f1.x);
        o[6] = (bhalf)((float)e[6] * f1.z - (float)e[7] * f1.w);
        o[7] = (bhalf)((float)e[6] * f1.w + (float)e[7] * f1.z);
        *(bhalf8*)(qb + ((size_t)(b * N_HEADS + h) * SEQ + s) * HD + d20 * 2) = o;
    }
    if (tid < 64) {
        const int kh = tid >> 4, d20 = (tid & 15) * 4;
        bhalf8 e = *(const bhalf8*)(row + 2048 + kh * HD + d20 * 2);
        const float* fp = freqs + (size_t)s * 128 + d20 * 2;
        float4 f0 = *(const float4*)fp;
        float4 f1 = *(const float4*)(fp + 4);
        bhalf8 o;
        o[0] = (bhalf)((float)e[0] * f0.x - (float)e[1] * f0.y);
        o[1] = (bhalf)((float)e[0] * f0.y + (float)e[1] * f0.x);
        o[2] = (bhalf)((float)e[2] * f0.z - (float)e[3] * f0.w);
        o[3] = (bhalf)((float)e[2] * f0.w + (float)e[3] * f0.z);
        o[4] = (bhalf)((float)e[4] * f1.x - (float)e[5] * f1.y);
        o[5] = (bhalf)((float)e[4] * f1.y + (float)e[5] * f1.x);
        o[6] = (bhalf)((float)e[6] * f1.z - (float)e[7] * f1.w);
        o[7] = (bhalf)((float)e[6] * f1.w + (float)e[7] * f1.z);
        *(bhalf8*)(kb + ((size_t)(b * N_KV + kh) * SEQ + s) * HD + d20 * 2) = o;
    }
}

// ---------------- V transpose via LDS tile: [s][d] -> [d][s] ---------------
// 256 blocks, each a 64s x 128d tile. Reads 256B rows coalesced; writes
// 128B s-runs coalesced per d-row. LDS: 64 rows x 256B, 16B slot XOR-swizzle
// slot ^= (s>>3)&7 -> column-gather u16 reads hit all 32 banks exactly once
// (bank = 4*j + (d>>1), d-parity pairs broadcast): zero conflicts.
__global__ __launch_bounds__(256) void vtrans_k(const bhalf* __restrict__ qkv,
                                                bhalf* __restrict__ vt) {
    const int blk = blockIdx.x;
    const int sc = blk & 31;
    const int kvh = (blk >> 5) & 3;
    const int b = blk >> 7;
    const int s0 = sc * 64;
    const int tid = threadIdx.x;
    __shared__ __align__(16) char lds[64 * 256];

    const int rr = tid >> 4;                 // row within pass
    const int slot = tid & 15;               // 16B slot (8 d-elems)
    #pragma unroll
    for (int p = 0; p < 4; ++p) {
        const int s = p * 16 + rr;
        bhalf8 v = *(const bhalf8*)(qkv + (size_t)(b * SEQ + s0 + s) * 3072
                                    + 2560 + kvh * HD + slot * 8);
        *(bhalf8*)(lds + s * 256 + ((slot ^ ((s >> 3) & 7)) << 4)) = v;
    }
    __syncthreads();
    const int j = tid & 7;                   // s8 slot of output row
    const int d0 = tid >> 3;                 // 0..31
    #pragma unroll
    for (int p = 0; p < 4; ++p) {
        const int d = p * 32 + d0;
        bhalf8 o;
        #pragma unroll
        for (int e = 0; e < 8; ++e) {
            const int s = j * 8 + e;
            o[e] = *(const bhalf*)(lds + s * 256 + (((d >> 3) ^ j) << 4) + (d & 7) * 2);
        }
        *(bhalf8*)(vt + ((size_t)(b * N_KV + kvh) * HD + d) * SEQ + s0 + j * 8) = o;
    }
}

// ---------------- Flash attention (R2-verified, unchanged) -----------------
__global__ __launch_bounds__(256, 2) void attn_k(const bhalf* __restrict__ qb,
                                                 const bhalf* __restrict__ kb,
                                                 const bhalf* __restrict__ vt,
                                                 bhalf* __restrict__ ob) {
    const int tid = threadIdx.x;
    const int wave = tid >> 6, lane = tid & 63;
    const int l31 = lane & 31, h2 = lane >> 5;
    const int qw = wave & 1, kw = wave >> 1;
    const int bid = ((blockIdx.x & 7) << 6) | ((int)blockIdx.x >> 3);
    const int pair = bid & 15;
    const int hh = (bid >> 4) & 15;
    const int b = bid >> 8;
    const int kvh = hh >> 2;

    __shared__ __align__(16) char smem[33792];
    char* const sK = smem;            // [64] rows x 256 B, swizzled
    char* const sV = smem + 16384;    // [128] rows x 128 B, swizzled
    float* const mrg = (float*)smem;  // phase-end merge buffer (aliases sK/sV)

    const bhalf* Kbase = kb + (size_t)(b * N_KV + kvh) * SEQ * HD;
    const bhalf* Vbase = vt + (size_t)(b * N_KV + kvh) * HD * SEQ;
    const float SCL2 = 0.08838834764831845f * 1.4426950408889634f;

    const int mbase = (qw * 64 + lane) * 66;
    const int kr = tid >> 4, kce = (tid & 15) * 8;
    const int vr = tid >> 3, vce = (tid & 7) * 8;
    const int kcB = kce * 2, vcB = vce * 2;
    const int Xl = (h2 << 4) ^ ((l31 & 7) << 4);

    for (int phase = 0; phase < 2; ++phase) {
        const int qt = phase ? (31 - pair) : pair;
        const int qrow = qt * 64 + qw * 32 + l31;
        const int qhi = qt * 64 + qw * 32 + 31;

        const bhalf* qbase = qb + (((size_t)(b * N_HEADS + hh) * SEQ) + qrow) * HD;
        bhalf8 qf[8];
        #pragma unroll
        for (int kk = 0; kk < 8; ++kk) {
            bhalf8 q0 = *(const bhalf8*)(qbase + kk * 16 + h2 * 8);
            #pragma unroll
            for (int e = 0; e < 8; ++e) q0[e] = (bhalf)((float)q0[e] * SCL2);
            qf[kk] = q0;
        }

        f32x16 accO[4];
        #pragma unroll
        for (int dt = 0; dt < 4; ++dt) accO[dt] = (f32x16)0.0f;
        float m_i = -1e30f, l_i = 0.0f;

        bhalf8 kreg[4], vreg[4];
        #pragma unroll
        for (int i = 0; i < 4; ++i) {
            kreg[i] = *(const bhalf8*)(Kbase + (size_t)(kr + 16 * i) * HD + kce);
            vreg[i] = *(const bhalf8*)(Vbase + (size_t)(vr + 32 * i) * SEQ + vce);
        }

        for (int kt = 0; kt <= qt; ++kt) {
            __syncthreads();
            #pragma unroll
            for (int i = 0; i < 4; ++i) {
                const int rk = kr + 16 * i;
                *(bhalf8*)(sK + rk * 256 + (kcB ^ ((rk & 7) << 4))) = kreg[i];
                const int rv = vr + 32 * i;
                *(bhalf8*)(sV + rv * 128 + (vcB ^ ((rv & 7) << 4))) = vreg[i];
            }
            __syncthreads();
            if (kt < qt) {
                const int kn = (kt + 1) * 64;
                #pragma unroll
                for (int i = 0; i < 4; ++i) {
                    kreg[i] = *(const bhalf8*)(Kbase + (size_t)(kn + kr + 16 * i) * HD + kce);
                    vreg[i] = *(const bhalf8*)(Vbase + (size_t)(vr + 32 * i) * SEQ + kn + vce);
                }
            }
            if (qhi < kt * 64 + kw * 32) continue;

            f32x16 accS = (f32x16)0.0f;
            const char* kRow = sK + (kw * 32 + l31) * 256;
            #pragma unroll
            for (int kk = 0; kk < 8; ++kk)
                accS = mfma32(*(const bhalf8*)(kRow + ((kk * 32) ^ Xl)), qf[kk], accS);

            if (kt == qt) {
                #pragma unroll
                for (int r = 0; r < 16; ++r) {
                    const int key = kt * 64 + kw * 32 + (r & 3) + 8 * (r >> 2) + 4 * h2;
                    if (key > qrow) accS[r] = -1e30f;
                }
            }

            float mx = -1e30f;
            #pragma unroll
            for (int r = 0; r < 16; ++r) mx = fmaxf(mx, accS[r]);
            mx = fmaxf(mx, __shfl_xor(mx, 32, 64));

            if (!__all(mx <= m_i + 8.0f)) {
                const float mnew = fmaxf(m_i, mx);
                const float alpha = __builtin_amdgcn_exp2f(m_i - mnew);
                m_i = mnew;
                l_i *= alpha;
                #pragma unroll
                for (int dt = 0; dt < 4; ++dt)
                    #pragma unroll
                    for (int r = 0; r < 16; ++r) accO[dt][r] *= alpha;
            }

            float p[16];
            float rs = 0.0f;
            #pragma unroll
            for (int r = 0; r < 16; ++r) {
                p[r] = __builtin_amdgcn_exp2f(accS[r] - m_i);
                rs += p[r];
            }
            rs += __shfl_xor(rs, 32, 64);
            l_i += rs;

            unsigned X0 = cvt_pk_bf16(p[0],  p[1]);
            unsigned X1 = cvt_pk_bf16(p[2],  p[3]);
            unsigned X2 = cvt_pk_bf16(p[4],  p[5]);
            unsigned X3 = cvt_pk_bf16(p[6],  p[7]);
            unsigned X4 = cvt_pk_bf16(p[8],  p[9]);
            unsigned X5 = cvt_pk_bf16(p[10], p[11]);
            unsigned X6 = cvt_pk_bf16(p[12], p[13]);
            unsigned X7 = cvt_pk_bf16(p[14], p[15]);
            plane32_swap(X0, X2);
            plane32_swap(X1, X3);
            plane32_swap(X4, X6);
            plane32_swap(X5, X7);
            union { unsigned u[8]; bhalf8 h[2]; } pk;
            pk.u[0] = X0; pk.u[1] = X1; pk.u[2] = X2; pk.u[3] = X3;
            pk.u[4] = X4; pk.u[5] = X5; pk.u[6] = X6; pk.u[7] = X7;

            #pragma unroll
            for (int kk2 = 0; kk2 < 2; ++kk2) {
                const int cb = (kw << 6) | (kk2 << 5);
                #pragma unroll
                for (int dt = 0; dt < 4; ++dt) {
                    const bhalf8 vfv = *(const bhalf8*)(sV + (dt * 32 + l31) * 128 + (cb ^ Xl));
                    accO[dt] = mfma32(vfv, pk.h[kk2], accO[dt]);
                }
            }
        }

        __syncthreads();
        if (kw == 1) {
            #pragma unroll
            for (int dt = 0; dt < 4; ++dt)
                #pragma unroll
                for (int r = 0; r < 16; ++r) mrg[mbase + dt * 16 + r] = accO[dt][r];
            mrg[mbase + 64] = m_i;
            mrg[mbase + 65] = l_i;
        }
        __syncthreads();
        if (kw == 0) {
            const float m1 = mrg[mbase + 64];
            const float l1 = mrg[mbase + 65];
            const float m = fmaxf(m_i, m1);
            const float b0 = __builtin_amdgcn_exp2f(m_i - m);
            const float b1 = __builtin_amdgcn_exp2f(m1 - m);
            const float inv = 1.0f / (l_i * b0 + l1 * b1);
            bhalf* obase = ob + ((size_t)b * SEQ + qrow) * (size_t)(N_HEADS * HD) + hh * HD;
            #pragma unroll
            for (int dt = 0; dt < 4; ++dt)
                #pragma unroll
                for (int c = 0; c < 4; ++c) {
                    bhalf4 o4;
                    #pragma unroll
                    for (int rr = 0; rr < 4; ++rr) {
                        const float v = accO[dt][c * 4 + rr] * b0 +
                                        mrg[mbase + dt * 16 + c * 4 + rr] * b1;
                        o4[rr] = (bhalf)(v * inv);
                    }
                    *(bhalf4*)(obase + dt * 32 + c * 8 + h2 * 4) = o4;
                }
        }
    }
}

extern "C" void kernel_launch(void* const* d_in, const int* in_sizes, int n_in,
                              void* d_out, int out_size, void* d_ws, size_t ws_size,
                              hipStream_t stream) {
    const float* x      = (const float*)d_in[0];
    const float* freqs  = (const float*)d_in[1];
    const float* norm_w = (const float*)d_in[2];
    const float* wqkv   = (const float*)d_in[3];
    const float* wo     = (const float*)d_in[4];
    float* out = (float*)d_out;

    char* ws = (char*)d_ws;
    bhalf* wqkv_b = (bhalf*)(ws);                      // 12,582,912
    bhalf* wo_b   = (bhalf*)(ws + 12582912);           //  8,388,608
    bhalf* xn     = (bhalf*)(ws + 20971520);           // 16,777,216
    bhalf* qkv    = (bhalf*)(ws + 37748736);           // 25,165,824 (bf16)
    bhalf* qb     = (bhalf*)(ws + 88080384);           // 16,777,216
    bhalf* kb     = (bhalf*)(ws + 104857600);          //  4,194,304
    bhalf* vtb    = (bhalf*)(ws + 109051904);          //  4,194,304
    bhalf* attn   = (bhalf*)(ws + 113246208);          // 16,777,216

    static bool attr_done = false;
    if (!attr_done) {
        hipFuncSetAttribute((const void*)gemm8p<bhalf>,
                            hipFuncAttributeMaxDynamicSharedMemorySize, 131072);
        attr_done = true;
    }

    cvt_w<<<10240, 256, 0, stream>>>(wqkv, wo, wqkv_b);
    rmsnorm_k<<<BATCH * SEQ, 256, 0, stream>>>(x, norm_w, xn);
    gemm8p<bhalf><<<192, 512, 131072, stream>>>(xn, wqkv_b, qkv, 3072, 2048);
    rope_k<<<BATCH * SEQ, 256, 0, stream>>>(qkv, freqs, qb, kb);
    vtrans_k<<<256, 256, 0, stream>>>(qkv, vtb);
    attn_k<<<512, 256, 0, stream>>>(qb, kb, vtb, attn);
    gemm128<float><<<512, 256, 0, stream>>>(attn, wo_b, out, 2048, 2048);
}

// Round 8
// 284.815 us; speedup vs baseline: 1.1099x; 1.0209x over previous
//
#include <hip/hip_runtime.h>
#include <cstdint>
#include <cstddef>

typedef __bf16 bhalf;
typedef __bf16 bhalf8 __attribute__((ext_vector_type(8)));
typedef __bf16 bhalf4 __attribute__((ext_vector_type(4)));
typedef float f32x4 __attribute__((ext_vector_type(4)));
typedef float f32x16 __attribute__((ext_vector_type(16)));

#define RMS_EPS 1e-6f
#define N_HEADS 16
#define N_KV 4
#define HD 128
#define DIM 2048
#define SEQ 2048
#define BATCH 2

static __device__ __forceinline__ f32x4 mfma16(bhalf8 a, bhalf8 b, f32x4 c) {
    return __builtin_amdgcn_mfma_f32_16x16x32_bf16(a, b, c, 0, 0, 0);
}
static __device__ __forceinline__ f32x16 mfma32(bhalf8 a, bhalf8 b, f32x16 c) {
    return __builtin_amdgcn_mfma_f32_32x32x16_bf16(a, b, c, 0, 0, 0);
}

// async global->LDS, 16B per lane; LDS base wave-uniform (HW adds lane*16)
static __device__ __forceinline__ void gload16(const bhalf* g, bhalf* l) {
    __builtin_amdgcn_global_load_lds((const __attribute__((address_space(1))) unsigned int*)g,
                                     (__attribute__((address_space(3))) unsigned int*)l,
                                     16, 0, 0);
}

// pack two f32 -> one u32 of 2x bf16 (lo = a, hi = b)
static __device__ __forceinline__ unsigned cvt_pk_bf16(float a, float b) {
    unsigned r;
    asm volatile("v_cvt_pk_bf16_f32 %0, %1, %2" : "=v"(r) : "v"(a), "v"(b));
    return r;
}
// swap upper 32 lanes of a with lower 32 lanes of b
static __device__ __forceinline__ void plane32_swap(unsigned& a, unsigned& b) {
    asm volatile("v_permlane32_swap_b32 %0, %1" : "+v"(a), "+v"(b));
}

// ---------------- fused prep: rmsnorm (blocks 0..4095) + w-convert --------
// Grid-partition fusion: one launch instead of two (saves ~12us dispatch gap).
__global__ __launch_bounds__(256) void prep_k(const float* __restrict__ x,
                                              const float* __restrict__ w,
                                              bhalf* __restrict__ xn,
                                              const float* __restrict__ wqkv,
                                              const float* __restrict__ wo,
                                              bhalf* __restrict__ wdst) {
    const int blk = blockIdx.x;
    const int tid = threadIdx.x;
    if (blk < BATCH * SEQ) {
        // ---- RMSNorm: one block per row ----
        const int row = blk;
        const float4* xr = (const float4*)(x + (size_t)row * DIM);
        float4 v0 = xr[tid * 2], v1 = xr[tid * 2 + 1];
        float ss = v0.x * v0.x + v0.y * v0.y + v0.z * v0.z + v0.w * v0.w
                 + v1.x * v1.x + v1.y * v1.y + v1.z * v1.z + v1.w * v1.w;
        #pragma unroll
        for (int off = 32; off; off >>= 1) ss += __shfl_xor(ss, off, 64);
        __shared__ float red[4];
        if ((tid & 63) == 0) red[tid >> 6] = ss;
        __syncthreads();
        float tot = red[0] + red[1] + red[2] + red[3];
        float scale = rsqrtf(tot * (1.0f / DIM) + RMS_EPS);
        const float4* wr = (const float4*)w;
        float4 w0 = wr[tid * 2], w1 = wr[tid * 2 + 1];
        bhalf8 o;
        o[0] = (bhalf)(v0.x * scale * w0.x); o[1] = (bhalf)(v0.y * scale * w0.y);
        o[2] = (bhalf)(v0.z * scale * w0.z); o[3] = (bhalf)(v0.w * scale * w0.w);
        o[4] = (bhalf)(v1.x * scale * w1.x); o[5] = (bhalf)(v1.y * scale * w1.y);
        o[6] = (bhalf)(v1.z * scale * w1.z); o[7] = (bhalf)(v1.w * scale * w1.w);
        *(bhalf8*)(xn + (size_t)row * DIM + tid * 8) = o;
    } else {
        // ---- weight convert f32 -> bf16 ----
        size_t i = ((size_t)(blk - BATCH * SEQ) * 256 + tid) * 4;
        const size_t NQ = (size_t)3072 * 2048;
        float4 v = (i < NQ) ? ((const float4*)wqkv)[i >> 2]
                            : ((const float4*)wo)[(i - NQ) >> 2];
        bhalf4 o;
        o[0] = (bhalf)v.x; o[1] = (bhalf)v.y; o[2] = (bhalf)v.z; o[3] = (bhalf)v.w;
        *(bhalf4*)(wdst + i) = o;
    }
}

// ---------------- GEMM: m201 8-phase 256x256 template, BK=64 (QKV) --------
// (R6-verified: bank-conflicts = 0, 67.9us on 192 blocks.)
template <typename OutT>
__global__ __launch_bounds__(512) void gemm8p(const bhalf* __restrict__ A,
                                              const bhalf* __restrict__ B,
                                              OutT* __restrict__ C,
                                              int N, int K) {
    extern __shared__ __align__(16) char smem[];
    const int tid = threadIdx.x;
    const int wid = tid >> 6, lane = tid & 63;
    const int quad = lane >> 4, r16 = lane & 15;
    const int wm = wid >> 2, wn = wid & 3;

    const int nx = N >> 8;
    const int cpx = (int)gridDim.x >> 3;
    const int bs = (int)blockIdx.x;
    const int bid = (bs & 7) * cpx + (bs >> 3);
    const int m0 = (bid / nx) << 8, n0 = (bid % nx) << 8;

    const int srow = wid * 8 + (lane >> 3);
    const int scol = ((lane & 7) ^ ((lane >> 3) & 7)) << 3;
    const bhalf* Asrc = A + (size_t)(m0 + srow) * K + scol;
    const bhalf* Bsrc = B + (size_t)(n0 + srow) * K + scol;
    const size_t r64K = (size_t)64 * K;
    const size_t r128K = (size_t)128 * K;

    const int x7 = r16 & 7;
    const int sl0 = (quad ^ (x7 & 3)) << 4;
    const int ksx = (x7 >> 2) << 6;
    const int k0 = ksx, k1 = 64 ^ ksx;
    const int aoff = (wm << 14) + (r16 << 7) + sl0;
    const int boff = ((2 + (wn >> 1)) << 14) + ((((wn & 1) << 6) + r16) << 7) + sl0;

    f32x4 acc[8][4];
    #pragma unroll
    for (int i = 0; i < 8; ++i)
        #pragma unroll
        for (int j = 0; j < 4; ++j) acc[i][j] = (f32x4)0.0f;

    const int NT = K >> 6;
    const int H = K >> 4;
    int h = 8;

    auto STAGE = [&](int hidx) {
        const int T = hidx >> 2, f = hidx & 3;
        const bhalf* s = ((f < 2) ? Asrc : Bsrc) + ((f & 1) ? r128K : 0) + T * 64;
        char* d = smem + ((T & 1) << 16) + (f << 14) + (wid << 10);
        gload16(s, (bhalf*)d);
        gload16(s + r64K, (bhalf*)(d + 8192));
    };

    #pragma unroll
    for (int i = 0; i < 8; ++i) STAGE(i);
    asm volatile("s_waitcnt vmcnt(8)" ::: "memory");
    __builtin_amdgcn_s_barrier();

    bhalf8 af[4][2], bf[4][2];

    for (int t = 0; t < NT; t += 2) {
        #pragma unroll
        for (int hf = 0; hf < 2; ++hf) {
            char* const bp = smem + (hf << 16);
            // phase 0
            #pragma unroll
            for (int i = 0; i < 4; ++i) {
                af[i][0] = *(const bhalf8*)(bp + aoff + i * 2048 + k0);
                af[i][1] = *(const bhalf8*)(bp + aoff + i * 2048 + k1);
            }
            #pragma unroll
            for (int j = 0; j < 2; ++j) {
                bf[j][0] = *(const bhalf8*)(bp + boff + j * 2048 + k0);
                bf[j][1] = *(const bhalf8*)(bp + boff + j * 2048 + k1);
            }
            if ((t > 0 || hf == 1) && h < H) STAGE(h++);
            asm volatile("s_waitcnt lgkmcnt(8)" ::: "memory");
            __builtin_amdgcn_s_barrier();
            __builtin_amdgcn_s_setprio(1);
            #pragma unroll
            for (int i = 0; i < 4; ++i)
                #pragma unroll
                for (int j = 0; j < 2; ++j) {
                    acc[i][j] = mfma16(af[i][0], bf[j][0], acc[i][j]);
                    acc[i][j] = mfma16(af[i][1], bf[j][1], acc[i][j]);
                }
            __builtin_amdgcn_s_setprio(0);
            __builtin_amdgcn_s_barrier();

            // phase 1
            #pragma unroll
            for (int j = 2; j < 4; ++j) {
                bf[j][0] = *(const bhalf8*)(bp + boff + j * 2048 + k0);
                bf[j][1] = *(const bhalf8*)(bp + boff + j * 2048 + k1);
            }
            if ((t > 0 || hf == 1) && h < H) STAGE(h++);
            __builtin_amdgcn_s_barrier();
            __builtin_amdgcn_s_setprio(1);
            #pragma unroll
            for (int i = 0; i < 4; ++i)
                #pragma unroll
                for (int j = 2; j < 4; ++j) {
                    acc[i][j] = mfma16(af[i][0], bf[j][0], acc[i][j]);
                    acc[i][j] = mfma16(af[i][1], bf[j][1], acc[i][j]);
                }
            __builtin_amdgcn_s_setprio(0);
            __builtin_amdgcn_s_barrier();

            // phase 2
            #pragma unroll
            for (int i = 0; i < 4; ++i) {
                af[i][0] = *(const bhalf8*)(bp + aoff + (i + 4) * 2048 + k0);
                af[i][1] = *(const bhalf8*)(bp + aoff + (i + 4) * 2048 + k1);
            }
            if ((t > 0 || hf == 1) && h < H) STAGE(h++);
            __builtin_amdgcn_s_barrier();
            __builtin_amdgcn_s_setprio(1);
            #pragma unroll
            for (int i = 0; i < 4; ++i)
                #pragma unroll
                for (int j = 0; j < 2; ++j) {
                    acc[i + 4][j] = mfma16(af[i][0], bf[j][0], acc[i + 4][j]);
                    acc[i + 4][j] = mfma16(af[i][1], bf[j][1], acc[i + 4][j]);
                }
            __builtin_amdgcn_s_setprio(0);
            __builtin_amdgcn_s_barrier();

            // phase 3 + vmcnt checkpoint
            bool st = (h < H);
            if (st) STAGE(h++);
            __builtin_amdgcn_s_barrier();
            __builtin_amdgcn_s_setprio(1);
            #pragma unroll
            for (int i = 0; i < 4; ++i)
                #pragma unroll
                for (int j = 2; j < 4; ++j) {
                    acc[i + 4][j] = mfma16(af[i][0], bf[j][0], acc[i + 4][j]);
                    acc[i + 4][j] = mfma16(af[i][1], bf[j][1], acc[i + 4][j]);
                }
            __builtin_amdgcn_s_setprio(0);
            if (st) asm volatile("s_waitcnt vmcnt(2)" ::: "memory");
            else    asm volatile("s_waitcnt vmcnt(0)" ::: "memory");
            __builtin_amdgcn_s_barrier();
        }
    }

    #pragma unroll
    for (int i = 0; i < 8; ++i) {
        const int rbase = m0 + wm * 128 + i * 16 + quad * 4;
        #pragma unroll
        for (int rr = 0; rr < 4; ++rr) {
            OutT* crow = C + (size_t)(rbase + rr) * N + n0 + wn * 64 + r16;
            #pragma unroll
            for (int j = 0; j < 4; ++j) crow[j * 16] = (OutT)acc[i][j][rr];
        }
    }
}

// ---------------- GEMM 128x128 (R4-verified): full-coverage WO -------------
template <typename OutT>
__global__ __launch_bounds__(256) void gemm128(const bhalf* __restrict__ A,
                                               const bhalf* __restrict__ B,
                                               OutT* __restrict__ C,
                                               int N, int K) {
    const int tid = threadIdx.x;
    const int w = tid >> 6, lane = tid & 63;
    const int quad = lane >> 4, r16 = lane & 15;
    const int wm = w >> 1, wn = w & 1;

    const int nx = N >> 7;
    const int cpx = (int)gridDim.x >> 3;
    const int bs = (int)blockIdx.x;
    const int bid = (bs & 7) * cpx + (bs >> 3);
    const int m0 = (bid / nx) << 7, n0 = (bid % nx) << 7;

    __shared__ __align__(16) char smem[49152];
    char* const sA = smem;
    char* const sB = smem + 24576;

    const int srow = lane >> 2;
    const int scol = ((lane & 3) ^ (srow & 3)) << 3;
    const bhalf* Ast = A + (size_t)(m0 + w * 16 + srow) * K + scol;
    const bhalf* Bst = B + (size_t)(n0 + w * 16 + srow) * K + scol;
    const size_t r64K = (size_t)64 * K;

    const int xorr = (r16 & 3) << 4;
    const int rdA = (wm * 64 + r16) * 64 + ((quad * 16) ^ xorr);
    const int rdB = (wn * 64 + r16) * 64 + ((quad * 16) ^ xorr);

    f32x4 acc[4][4];
    #pragma unroll
    for (int i = 0; i < 4; ++i)
        #pragma unroll
        for (int j = 0; j < 4; ++j) acc[i][j] = (f32x4)0.0f;

    const int NT = K >> 5;

    #define STG128(t, buf) do {                                                        \
        gload16(Ast + (size_t)(t) * 32,        (bhalf*)(sA + (buf) * 8192 + w * 1024));        \
        gload16(Ast + (size_t)(t) * 32 + r64K, (bhalf*)(sA + (buf) * 8192 + 4096 + w * 1024)); \
        gload16(Bst + (size_t)(t) * 32,        (bhalf*)(sB + (buf) * 8192 + w * 1024));        \
        gload16(Bst + (size_t)(t) * 32 + r64K, (bhalf*)(sB + (buf) * 8192 + 4096 + w * 1024)); \
    } while (0)

    STG128(0, 0);
    STG128(1, 1);

    int cur = 0, c2 = 2;
    for (int t = 0; t < NT; ++t) {
        if (t + 1 < NT) asm volatile("s_waitcnt vmcnt(4)" ::: "memory");
        else            asm volatile("s_waitcnt vmcnt(0)" ::: "memory");
        __builtin_amdgcn_s_barrier();

        char* const bufA = sA + cur * 8192;
        char* const bufB = sB + cur * 8192;
        bhalf8 af[4], bf[4];
        #pragma unroll
        for (int i = 0; i < 4; ++i) af[i] = *(const bhalf8*)(bufA + rdA + i * 1024);
        #pragma unroll
        for (int j = 0; j < 4; ++j) bf[j] = *(const bhalf8*)(bufB + rdB + j * 1024);

        if (t + 2 < NT) STG128(t + 2, c2);

        __builtin_amdgcn_s_setprio(1);
        #pragma unroll
        for (int i = 0; i < 4; ++i)
            #pragma unroll
            for (int j = 0; j < 4; ++j)
                acc[i][j] = mfma16(af[i], bf[j], acc[i][j]);
        __builtin_amdgcn_s_setprio(0);

        cur = (cur == 2) ? 0 : cur + 1;
        c2 = (c2 == 2) ? 0 : c2 + 1;
    }
    #undef STG128

    #pragma unroll
    for (int i = 0; i < 4; ++i) {
        const int rbase = m0 + wm * 64 + i * 16 + quad * 4;
        #pragma unroll
        for (int rr = 0; rr < 4; ++rr) {
            OutT* crow = C + (size_t)(rbase + rr) * N + n0 + wn * 64 + r16;
            #pragma unroll
            for (int j = 0; j < 4; ++j) crow[j * 16] = (OutT)acc[i][j][rr];
        }
    }
}

// ---------------- fused RoPE q/k (blocks 0..4095) + V transpose ------------
__global__ __launch_bounds__(256) void rope_k(const bhalf* __restrict__ qkv,
                                              const float* __restrict__ freqs,
                                              bhalf* __restrict__ qb,
                                              bhalf* __restrict__ kb,
                                              bhalf* __restrict__ vt) {
    const int blk = blockIdx.x;
    const int tid = threadIdx.x;
    if (blk < BATCH * SEQ) {
        const int b = blk >> 11, s = blk & 2047;
        const bhalf* row = qkv + (size_t)blk * 3072;
        {
            const int h = tid >> 4, d20 = (tid & 15) * 4;
            bhalf8 e = *(const bhalf8*)(row + h * HD + d20 * 2);
            const float* fp = freqs + (size_t)s * 128 + d20 * 2;
            float4 f0 = *(const float4*)fp;
            float4 f1 = *(const float4*)(fp + 4);
            bhalf8 o;
            o[0] = (bhalf)((float)e[0] * f0.x - (float)e[1] * f0.y);
            o[1] = (bhalf)((float)e[0] * f0.y + (float)e[1] * f0.x);
            o[2] = (bhalf)((float)e[2] * f0.z - (float)e[3] * f0.w);
            o[3] = (bhalf)((float)e[2] * f0.w + (float)e[3] * f0.z);
            o[4] = (bhalf)((float)e[4] * f1.x - (float)e[5] * f1.y);
            o[5] = (bhalf)((float)e[4] * f1.y + (float)e[5] * f1.x);
            o[6] = (bhalf)((float)e[6] * f1.z - (float)e[7] * f1.w);
            o[7] = (bhalf)((float)e[6] * f1.w + (float)e[7] * f1.z);
            *(bhalf8*)(qb + ((size_t)(b * N_HEADS + h) * SEQ + s) * HD + d20 * 2) = o;
        }
        if (tid < 64) {
            const int kh = tid >> 4, d20 = (tid & 15) * 4;
            bhalf8 e = *(const bhalf8*)(row + 2048 + kh * HD + d20 * 2);
            const float* fp = freqs + (size_t)s * 128 + d20 * 2;
            float4 f0 = *(const float4*)fp;
            float4 f1 = *(const float4*)(fp + 4);
            bhalf8 o;
            o[0] = (bhalf)((float)e[0] * f0.x - (float)e[1] * f0.y);
            o[1] = (bhalf)((float)e[0] * f0.y + (float)e[1] * f0.x);
            o[2] = (bhalf)((float)e[2] * f0.z - (float)e[3] * f0.w);
            o[3] = (bhalf)((float)e[2] * f0.w + (float)e[3] * f0.z);
            o[4] = (bhalf)((float)e[4] * f1.x - (float)e[5] * f1.y);
            o[5] = (bhalf)((float)e[4] * f1.y + (float)e[5] * f1.x);
            o[6] = (bhalf)((float)e[6] * f1.z - (float)e[7] * f1.w);
            o[7] = (bhalf)((float)e[6] * f1.w + (float)e[7] * f1.z);
            *(bhalf8*)(kb + ((size_t)(b * N_KV + kh) * SEQ + s) * HD + d20 * 2) = o;
        }
    } else {
        // ---- V transpose via LDS tile: [s][d] -> [d][s], zero-conflict ----
        const int vb = blk - BATCH * SEQ;
        const int sc = vb & 31;
        const int kvh = (vb >> 5) & 3;
        const int b = vb >> 7;
        const int s0 = sc * 64;
        __shared__ __align__(16) char lds[64 * 256];

        const int rr = tid >> 4;
        const int slot = tid & 15;
        #pragma unroll
        for (int p = 0; p < 4; ++p) {
            const int s = p * 16 + rr;
            bhalf8 v = *(const bhalf8*)(qkv + (size_t)(b * SEQ + s0 + s) * 3072
                                        + 2560 + kvh * HD + slot * 8);
            *(bhalf8*)(lds + s * 256 + ((slot ^ ((s >> 3) & 7)) << 4)) = v;
        }
        __syncthreads();
        const int j = tid & 7;
        const int d0 = tid >> 3;
        #pragma unroll
        for (int p = 0; p < 4; ++p) {
            const int d = p * 32 + d0;
            bhalf8 o;
            #pragma unroll
            for (int e = 0; e < 8; ++e) {
                const int s = j * 8 + e;
                o[e] = *(const bhalf*)(lds + s * 256 + (((d >> 3) ^ j) << 4) + (d & 7) * 2);
            }
            *(bhalf8*)(vt + ((size_t)(b * N_KV + kvh) * HD + d) * SEQ + s0 + j * 8) = o;
        }
    }
}

// ---------------- Flash attention (R2-verified + T5 setprio) ---------------
__global__ __launch_bounds__(256, 2) void attn_k(const bhalf* __restrict__ qb,
                                                 const bhalf* __restrict__ kb,
                                                 const bhalf* __restrict__ vt,
                                                 bhalf* __restrict__ ob) {
    const int tid = threadIdx.x;
    const int wave = tid >> 6, lane = tid & 63;
    const int l31 = lane & 31, h2 = lane >> 5;
    const int qw = wave & 1, kw = wave >> 1;
    const int bid = ((blockIdx.x & 7) << 6) | ((int)blockIdx.x >> 3);
    const int pair = bid & 15;
    const int hh = (bid >> 4) & 15;
    const int b = bid >> 8;
    const int kvh = hh >> 2;

    __shared__ __align__(16) char smem[33792];
    char* const sK = smem;            // [64] rows x 256 B, swizzled
    char* const sV = smem + 16384;    // [128] rows x 128 B, swizzled
    float* const mrg = (float*)smem;  // phase-end merge buffer (aliases sK/sV)

    const bhalf* Kbase = kb + (size_t)(b * N_KV + kvh) * SEQ * HD;
    const bhalf* Vbase = vt + (size_t)(b * N_KV + kvh) * HD * SEQ;
    const float SCL2 = 0.08838834764831845f * 1.4426950408889634f;

    const int mbase = (qw * 64 + lane) * 66;
    const int kr = tid >> 4, kce = (tid & 15) * 8;
    const int vr = tid >> 3, vce = (tid & 7) * 8;
    const int kcB = kce * 2, vcB = vce * 2;
    const int Xl = (h2 << 4) ^ ((l31 & 7) << 4);

    for (int phase = 0; phase < 2; ++phase) {
        const int qt = phase ? (31 - pair) : pair;
        const int qrow = qt * 64 + qw * 32 + l31;
        const int qhi = qt * 64 + qw * 32 + 31;

        const bhalf* qbase = qb + (((size_t)(b * N_HEADS + hh) * SEQ) + qrow) * HD;
        bhalf8 qf[8];
        #pragma unroll
        for (int kk = 0; kk < 8; ++kk) {
            bhalf8 q0 = *(const bhalf8*)(qbase + kk * 16 + h2 * 8);
            #pragma unroll
            for (int e = 0; e < 8; ++e) q0[e] = (bhalf)((float)q0[e] * SCL2);
            qf[kk] = q0;
        }

        f32x16 accO[4];
        #pragma unroll
        for (int dt = 0; dt < 4; ++dt) accO[dt] = (f32x16)0.0f;
        float m_i = -1e30f, l_i = 0.0f;

        bhalf8 kreg[4], vreg[4];
        #pragma unroll
        for (int i = 0; i < 4; ++i) {
            kreg[i] = *(const bhalf8*)(Kbase + (size_t)(kr + 16 * i) * HD + kce);
            vreg[i] = *(const bhalf8*)(Vbase + (size_t)(vr + 32 * i) * SEQ + vce);
        }

        for (int kt = 0; kt <= qt; ++kt) {
            __syncthreads();
            #pragma unroll
            for (int i = 0; i < 4; ++i) {
                const int rk = kr + 16 * i;
                *(bhalf8*)(sK + rk * 256 + (kcB ^ ((rk & 7) << 4))) = kreg[i];
                const int rv = vr + 32 * i;
                *(bhalf8*)(sV + rv * 128 + (vcB ^ ((rv & 7) << 4))) = vreg[i];
            }
            __syncthreads();
            if (kt < qt) {
                const int kn = (kt + 1) * 64;
                #pragma unroll
                for (int i = 0; i < 4; ++i) {
                    kreg[i] = *(const bhalf8*)(Kbase + (size_t)(kn + kr + 16 * i) * HD + kce);
                    vreg[i] = *(const bhalf8*)(Vbase + (size_t)(vr + 32 * i) * SEQ + kn + vce);
                }
            }
            if (qhi < kt * 64 + kw * 32) continue;

            f32x16 accS = (f32x16)0.0f;
            const char* kRow = sK + (kw * 32 + l31) * 256;
            __builtin_amdgcn_s_setprio(1);
            #pragma unroll
            for (int kk = 0; kk < 8; ++kk)
                accS = mfma32(*(const bhalf8*)(kRow + ((kk * 32) ^ Xl)), qf[kk], accS);
            __builtin_amdgcn_s_setprio(0);

            if (kt == qt) {
                #pragma unroll
                for (int r = 0; r < 16; ++r) {
                    const int key = kt * 64 + kw * 32 + (r & 3) + 8 * (r >> 2) + 4 * h2;
                    if (key > qrow) accS[r] = -1e30f;
                }
            }

            float mx = -1e30f;
            #pragma unroll
            for (int r = 0; r < 16; ++r) mx = fmaxf(mx, accS[r]);
            mx = fmaxf(mx, __shfl_xor(mx, 32, 64));

            if (!__all(mx <= m_i + 8.0f)) {
                const float mnew = fmaxf(m_i, mx);
                const float alpha = __builtin_amdgcn_exp2f(m_i - mnew);
                m_i = mnew;
                l_i *= alpha;
                #pragma unroll
                for (int dt = 0; dt < 4; ++dt)
                    #pragma unroll
                    for (int r = 0; r < 16; ++r) accO[dt][r] *= alpha;
            }

            float p[16];
            float rs = 0.0f;
            #pragma unroll
            for (int r = 0; r < 16; ++r) {
                p[r] = __builtin_amdgcn_exp2f(accS[r] - m_i);
                rs += p[r];
            }
            rs += __shfl_xor(rs, 32, 64);
            l_i += rs;

            unsigned X0 = cvt_pk_bf16(p[0],  p[1]);
            unsigned X1 = cvt_pk_bf16(p[2],  p[3]);
            unsigned X2 = cvt_pk_bf16(p[4],  p[5]);
            unsigned X3 = cvt_pk_bf16(p[6],  p[7]);
            unsigned X4 = cvt_pk_bf16(p[8],  p[9]);
            unsigned X5 = cvt_pk_bf16(p[10], p[11]);
            unsigned X6 = cvt_pk_bf16(p[12], p[13]);
            unsigned X7 = cvt_pk_bf16(p[14], p[15]);
            plane32_swap(X0, X2);
            plane32_swap(X1, X3);
            plane32_swap(X4, X6);
            plane32_swap(X5, X7);
            union { unsigned u[8]; bhalf8 h[2]; } pk;
            pk.u[0] = X0; pk.u[1] = X1; pk.u[2] = X2; pk.u[3] = X3;
            pk.u[4] = X4; pk.u[5] = X5; pk.u[6] = X6; pk.u[7] = X7;

            __builtin_amdgcn_s_setprio(1);
            #pragma unroll
            for (int kk2 = 0; kk2 < 2; ++kk2) {
                const int cb = (kw << 6) | (kk2 << 5);
                #pragma unroll
                for (int dt = 0; dt < 4; ++dt) {
                    const bhalf8 vfv = *(const bhalf8*)(sV + (dt * 32 + l31) * 128 + (cb ^ Xl));
                    accO[dt] = mfma32(vfv, pk.h[kk2], accO[dt]);
                }
            }
            __builtin_amdgcn_s_setprio(0);
        }

        __syncthreads();
        if (kw == 1) {
            #pragma unroll
            for (int dt = 0; dt < 4; ++dt)
                #pragma unroll
                for (int r = 0; r < 16; ++r) mrg[mbase + dt * 16 + r] = accO[dt][r];
            mrg[mbase + 64] = m_i;
            mrg[mbase + 65] = l_i;
        }
        __syncthreads();
        if (kw == 0) {
            const float m1 = mrg[mbase + 64];
            const float l1 = mrg[mbase + 65];
            const float m = fmaxf(m_i, m1);
            const float b0 = __builtin_amdgcn_exp2f(m_i - m);
            const float b1 = __builtin_amdgcn_exp2f(m1 - m);
            const float inv = 1.0f / (l_i * b0 + l1 * b1);
            bhalf* obase = ob + ((size_t)b * SEQ + qrow) * (size_t)(N_HEADS * HD) + hh * HD;
            #pragma unroll
            for (int dt = 0; dt < 4; ++dt)
                #pragma unroll
                for (int c = 0; c < 4; ++c) {
                    bhalf4 o4;
                    #pragma unroll
                    for (int rr = 0; rr < 4; ++rr) {
                        const float v = accO[dt][c * 4 + rr] * b0 +
                                        mrg[mbase + dt * 16 + c * 4 + rr] * b1;
                        o4[rr] = (bhalf)(v * inv);
                    }
                    *(bhalf4*)(obase + dt * 32 + c * 8 + h2 * 4) = o4;
                }
        }
    }
}

extern "C" void kernel_launch(void* const* d_in, const int* in_sizes, int n_in,
                              void* d_out, int out_size, void* d_ws, size_t ws_size,
                              hipStream_t stream) {
    const float* x      = (const float*)d_in[0];
    const float* freqs  = (const float*)d_in[1];
    const float* norm_w = (const float*)d_in[2];
    const float* wqkv   = (const float*)d_in[3];
    const float* wo     = (const float*)d_in[4];
    float* out = (float*)d_out;

    char* ws = (char*)d_ws;
    bhalf* wqkv_b = (bhalf*)(ws);                      // 12,582,912
    bhalf* wo_b   = (bhalf*)(ws + 12582912);           //  8,388,608
    bhalf* xn     = (bhalf*)(ws + 20971520);           // 16,777,216
    bhalf* qkv    = (bhalf*)(ws + 37748736);           // 25,165,824 (bf16)
    bhalf* qb     = (bhalf*)(ws + 88080384);           // 16,777,216
    bhalf* kb     = (bhalf*)(ws + 104857600);          //  4,194,304
    bhalf* vtb    = (bhalf*)(ws + 109051904);          //  4,194,304
    bhalf* attn   = (bhalf*)(ws + 113246208);          // 16,777,216

    static bool attr_done = false;
    if (!attr_done) {
        hipFuncSetAttribute((const void*)gemm8p<bhalf>,
                            hipFuncAttributeMaxDynamicSharedMemorySize, 131072);
        attr_done = true;
    }

    // 5 launches (was 7): rmsnorm+cvt fused, rope+vtrans fused.
    prep_k<<<BATCH * SEQ + 10240, 256, 0, stream>>>(x, norm_w, xn, wqkv, wo, wqkv_b);
    gemm8p<bhalf><<<192, 512, 131072, stream>>>(xn, wqkv_b, qkv, 3072, 2048);
    rope_k<<<BATCH * SEQ + 256, 256, 0, stream>>>(qkv, freqs, qb, kb, vtb);
    attn_k<<<512, 256, 0, stream>>>(qb, kb, vtb, attn);
    gemm128<float><<<512, 256, 0, stream>>>(attn, wo_b, out, 2048, 2048);
}

// Round 9
// 280.794 us; speedup vs baseline: 1.1257x; 1.0143x over previous
//
#include <hip/hip_runtime.h>
#include <cstdint>
#include <cstddef>

typedef __bf16 bhalf;
typedef __bf16 bhalf8 __attribute__((ext_vector_type(8)));
typedef __bf16 bhalf4 __attribute__((ext_vector_type(4)));
typedef float f32x4 __attribute__((ext_vector_type(4)));
typedef float f32x16 __attribute__((ext_vector_type(16)));

#define RMS_EPS 1e-6f
#define N_HEADS 16
#define N_KV 4
#define HD 128
#define DIM 2048
#define SEQ 2048
#define BATCH 2

static __device__ __forceinline__ f32x4 mfma16(bhalf8 a, bhalf8 b, f32x4 c) {
    return __builtin_amdgcn_mfma_f32_16x16x32_bf16(a, b, c, 0, 0, 0);
}
static __device__ __forceinline__ f32x16 mfma32(bhalf8 a, bhalf8 b, f32x16 c) {
    return __builtin_amdgcn_mfma_f32_32x32x16_bf16(a, b, c, 0, 0, 0);
}

// async global->LDS, 16B per lane; LDS base wave-uniform (HW adds lane*16)
static __device__ __forceinline__ void gload16(const bhalf* g, bhalf* l) {
    __builtin_amdgcn_global_load_lds((const __attribute__((address_space(1))) unsigned int*)g,
                                     (__attribute__((address_space(3))) unsigned int*)l,
                                     16, 0, 0);
}

// pack two f32 -> one u32 of 2x bf16 (lo = a, hi = b)
static __device__ __forceinline__ unsigned cvt_pk_bf16(float a, float b) {
    unsigned r;
    asm volatile("v_cvt_pk_bf16_f32 %0, %1, %2" : "=v"(r) : "v"(a), "v"(b));
    return r;
}
// swap upper 32 lanes of a with lower 32 lanes of b
static __device__ __forceinline__ void plane32_swap(unsigned& a, unsigned& b) {
    asm volatile("v_permlane32_swap_b32 %0, %1" : "+v"(a), "+v"(b));
}

// ---------------- fused prep: rmsnorm (blocks 0..4095) + w-convert --------
__global__ __launch_bounds__(256) void prep_k(const float* __restrict__ x,
                                              const float* __restrict__ w,
                                              bhalf* __restrict__ xn,
                                              const float* __restrict__ wqkv,
                                              const float* __restrict__ wo,
                                              bhalf* __restrict__ wdst) {
    const int blk = blockIdx.x;
    const int tid = threadIdx.x;
    if (blk < BATCH * SEQ) {
        const int row = blk;
        const float4* xr = (const float4*)(x + (size_t)row * DIM);
        float4 v0 = xr[tid * 2], v1 = xr[tid * 2 + 1];
        float ss = v0.x * v0.x + v0.y * v0.y + v0.z * v0.z + v0.w * v0.w
                 + v1.x * v1.x + v1.y * v1.y + v1.z * v1.z + v1.w * v1.w;
        #pragma unroll
        for (int off = 32; off; off >>= 1) ss += __shfl_xor(ss, off, 64);
        __shared__ float red[4];
        if ((tid & 63) == 0) red[tid >> 6] = ss;
        __syncthreads();
        float tot = red[0] + red[1] + red[2] + red[3];
        float scale = rsqrtf(tot * (1.0f / DIM) + RMS_EPS);
        const float4* wr = (const float4*)w;
        float4 w0 = wr[tid * 2], w1 = wr[tid * 2 + 1];
        bhalf8 o;
        o[0] = (bhalf)(v0.x * scale * w0.x); o[1] = (bhalf)(v0.y * scale * w0.y);
        o[2] = (bhalf)(v0.z * scale * w0.z); o[3] = (bhalf)(v0.w * scale * w0.w);
        o[4] = (bhalf)(v1.x * scale * w1.x); o[5] = (bhalf)(v1.y * scale * w1.y);
        o[6] = (bhalf)(v1.z * scale * w1.z); o[7] = (bhalf)(v1.w * scale * w1.w);
        *(bhalf8*)(xn + (size_t)row * DIM + tid * 8) = o;
    } else {
        size_t i = ((size_t)(blk - BATCH * SEQ) * 256 + tid) * 4;
        const size_t NQ = (size_t)3072 * 2048;
        float4 v = (i < NQ) ? ((const float4*)wqkv)[i >> 2]
                            : ((const float4*)wo)[(i - NQ) >> 2];
        bhalf4 o;
        o[0] = (bhalf)v.x; o[1] = (bhalf)v.y; o[2] = (bhalf)v.z; o[3] = (bhalf)v.w;
        *(bhalf4*)(wdst + i) = o;
    }
}

// ---------------- GEMM QKV: 256x192 tile, grid 256 = 1 block/CU exact -----
// 8 waves (2M x 4N), per-wave 128x48 (acc[8][3]). LDS 112KB: 2 buf x
// {A: 4 x 8KB sub-blocks (64 rows x 128B), B: 3 x 8KB}. 4 phases/K-tile:
//  ph0: read A i0-3 + B j0-1 (12 b128); MFMA 16    | stage T+1: B0,B1
//  ph1: read B j2 (2);               MFMA 8        | stage T+1: B2,A0
//       -> vmcnt(4) before end barrier: drains prior tile's A3 (exact count:
//          1 stale + 4 fresh outstanding) before its ph2 read. tail: vmcnt(0)
//  ph2: read A i4-7 (8);             MFMA 16       | stage T+1: A2,A1
//  ph3: (no reads)                   MFMA 8        | stage T+1: A3
//       -> vmcnt(1): leaves ONLY T+1's A3 in flight (read at T+1.ph2,
//          guarded by T+1's ph1 checkpoint). All cross-wave reads covered:
//          each wave's own counted wait + barrier => no latency assumptions.
// Units ordered by read phase (early-read staged earliest). Swizzle: 16B
// slot ^= (row&7) within 128B rows; gload_lds dest linear, global source
// pre-swizzled, reads apply the same involution (rule #21).
__global__ __launch_bounds__(512) void gemmq(const bhalf* __restrict__ A,
                                             const bhalf* __restrict__ B,
                                             bhalf* __restrict__ C,
                                             int N, int K) {
    extern __shared__ __align__(16) char smem[];
    const int tid = threadIdx.x;
    const int wid = tid >> 6, lane = tid & 63;
    const int quad = lane >> 4, r16 = lane & 15;
    const int wm = wid >> 2, wn = wid & 3;

    const int nx = N / 192;                    // 16
    const int cpx = (int)gridDim.x >> 3;       // 32
    const int bs = (int)blockIdx.x;
    const int bid = (bs & 7) * cpx + (bs >> 3);
    const int m0 = (bid / nx) << 8, n0 = (bid % nx) * 192;

    // stage source: per-lane global addr with pre-swizzled 16B slot
    const int srow = wid * 8 + (lane >> 3);                    // 0..63
    const int scol = ((lane & 7) ^ ((lane >> 3) & 7)) << 3;    // swizzled col
    const bhalf* Asrc = A + (size_t)(m0 + srow) * K + scol;
    const bhalf* Bsrc = B + (size_t)(n0 + srow) * K + scol;

    // ds_read swizzled offsets
    const int x7 = r16 & 7;
    const int sl0 = (quad ^ (x7 & 3)) << 4;
    const int ksx = (x7 >> 2) << 6;
    const int k0 = ksx, k1 = 64 ^ ksx;
    int aofs[8], bofs[3];
    #pragma unroll
    for (int i = 0; i < 8; ++i) {
        const int g = wm * 128 + i * 16 + r16;
        aofs[i] = ((g >> 6) << 13) + ((g & 63) << 7) + sl0;
    }
    #pragma unroll
    for (int j = 0; j < 3; ++j) {
        const int g = wn * 48 + j * 16 + r16;
        bofs[j] = 32768 + ((g >> 6) << 13) + ((g & 63) << 7) + sl0;
    }

    // stage one 64-row unit of tile T: 512 threads x 16B = 8KB
    auto STG = [&](int T, const bhalf* base, int rowb, int lreg) {
        gload16(base + (size_t)rowb * K + (size_t)T * 64,
                (bhalf*)(smem + (T & 1) * 57344 + lreg + wid * 1024));
    };

    f32x4 acc[8][3];
    #pragma unroll
    for (int i = 0; i < 8; ++i)
        #pragma unroll
        for (int j = 0; j < 3; ++j) acc[i][j] = (f32x4)0.0f;

    const int NT = K >> 6;   // 64-wide K tiles

    // prologue: tiles 0 and 1 (14 units); vmcnt(7) -> tile 0 fully landed
    #pragma unroll
    for (int T = 0; T < 2; ++T) {
        STG(T, Bsrc, 0, 32768); STG(T, Bsrc, 64, 40960); STG(T, Bsrc, 128, 49152);
        STG(T, Asrc, 0, 0);     STG(T, Asrc, 128, 16384);
        STG(T, Asrc, 64, 8192); STG(T, Asrc, 192, 24576);
    }
    asm volatile("s_waitcnt vmcnt(7)" ::: "memory");
    __builtin_amdgcn_s_barrier();

    for (int t = 0; t < NT; ++t) {
        char* const bp = smem + (t & 1) * 57344;
        const bool stg = (t > 0) && (t + 1 < NT);
        const int tn = t + 1;
        const bool last = (t + 1 == NT);

        // ---- phase 0: A i0-3 + B j0-1; MFMA lowA x lowB ----
        bhalf8 af[4][2], bf[3][2];
        #pragma unroll
        for (int i = 0; i < 4; ++i) {
            af[i][0] = *(const bhalf8*)(bp + aofs[i] + k0);
            af[i][1] = *(const bhalf8*)(bp + aofs[i] + k1);
        }
        #pragma unroll
        for (int j = 0; j < 2; ++j) {
            bf[j][0] = *(const bhalf8*)(bp + bofs[j] + k0);
            bf[j][1] = *(const bhalf8*)(bp + bofs[j] + k1);
        }
        if (stg) { STG(tn, Bsrc, 0, 32768); STG(tn, Bsrc, 64, 40960); }
        asm volatile("s_waitcnt lgkmcnt(8)" ::: "memory");
        __builtin_amdgcn_s_barrier();
        __builtin_amdgcn_s_setprio(1);
        #pragma unroll
        for (int i = 0; i < 4; ++i)
            #pragma unroll
            for (int j = 0; j < 2; ++j) {
                acc[i][j] = mfma16(af[i][0], bf[j][0], acc[i][j]);
                acc[i][j] = mfma16(af[i][1], bf[j][1], acc[i][j]);
            }
        __builtin_amdgcn_s_setprio(0);
        __builtin_amdgcn_s_barrier();

        // ---- phase 1: B j2; MFMA lowA x j2; checkpoint (prior tile's A3) --
        bf[2][0] = *(const bhalf8*)(bp + bofs[2] + k0);
        bf[2][1] = *(const bhalf8*)(bp + bofs[2] + k1);
        if (stg) { STG(tn, Bsrc, 128, 49152); STG(tn, Asrc, 0, 0); }
        __builtin_amdgcn_s_barrier();
        __builtin_amdgcn_s_setprio(1);
        #pragma unroll
        for (int i = 0; i < 4; ++i) {
            acc[i][2] = mfma16(af[i][0], bf[2][0], acc[i][2]);
            acc[i][2] = mfma16(af[i][1], bf[2][1], acc[i][2]);
        }
        __builtin_amdgcn_s_setprio(0);
        if (!last) asm volatile("s_waitcnt vmcnt(4)" ::: "memory");
        else       asm volatile("s_waitcnt vmcnt(0)" ::: "memory");
        __builtin_amdgcn_s_barrier();

        // ---- phase 2: A i4-7; MFMA highA x lowB ----
        #pragma unroll
        for (int i = 0; i < 4; ++i) {
            af[i][0] = *(const bhalf8*)(bp + aofs[i + 4] + k0);
            af[i][1] = *(const bhalf8*)(bp + aofs[i + 4] + k1);
        }
        if (stg) { STG(tn, Asrc, 128, 16384); STG(tn, Asrc, 64, 8192); }
        __builtin_amdgcn_s_barrier();
        __builtin_amdgcn_s_setprio(1);
        #pragma unroll
        for (int i = 0; i < 4; ++i)
            #pragma unroll
            for (int j = 0; j < 2; ++j) {
                acc[i + 4][j] = mfma16(af[i][0], bf[j][0], acc[i + 4][j]);
                acc[i + 4][j] = mfma16(af[i][1], bf[j][1], acc[i + 4][j]);
            }
        __builtin_amdgcn_s_setprio(0);
        __builtin_amdgcn_s_barrier();

        // ---- phase 3: MFMA highA x j2; stage A3; checkpoint vmcnt(1) ----
        if (stg) STG(tn, Asrc, 192, 24576);
        __builtin_amdgcn_s_barrier();
        __builtin_amdgcn_s_setprio(1);
        #pragma unroll
        for (int i = 0; i < 4; ++i) {
            acc[i + 4][2] = mfma16(af[i][0], bf[2][0], acc[i + 4][2]);
            acc[i + 4][2] = mfma16(af[i][1], bf[2][1], acc[i + 4][2]);
        }
        __builtin_amdgcn_s_setprio(0);
        if (!last) asm volatile("s_waitcnt vmcnt(1)" ::: "memory");
        else       asm volatile("s_waitcnt vmcnt(0)" ::: "memory");
        __builtin_amdgcn_s_barrier();
    }

    #pragma unroll
    for (int i = 0; i < 8; ++i) {
        const int rbase = m0 + wm * 128 + i * 16 + quad * 4;
        #pragma unroll
        for (int rr = 0; rr < 4; ++rr) {
            bhalf* crow = C + (size_t)(rbase + rr) * N + n0 + wn * 48 + r16;
            #pragma unroll
            for (int j = 0; j < 3; ++j) crow[j * 16] = (bhalf)acc[i][j][rr];
        }
    }
}

// ---------------- GEMM 128x128 (R4-verified): full-coverage WO -------------
template <typename OutT>
__global__ __launch_bounds__(256) void gemm128(const bhalf* __restrict__ A,
                                               const bhalf* __restrict__ B,
                                               OutT* __restrict__ C,
                                               int N, int K) {
    const int tid = threadIdx.x;
    const int w = tid >> 6, lane = tid & 63;
    const int quad = lane >> 4, r16 = lane & 15;
    const int wm = w >> 1, wn = w & 1;

    const int nx = N >> 7;
    const int cpx = (int)gridDim.x >> 3;
    const int bs = (int)blockIdx.x;
    const int bid = (bs & 7) * cpx + (bs >> 3);
    const int m0 = (bid / nx) << 7, n0 = (bid % nx) << 7;

    __shared__ __align__(16) char smem[49152];
    char* const sA = smem;
    char* const sB = smem + 24576;

    const int srow = lane >> 2;
    const int scol = ((lane & 3) ^ (srow & 3)) << 3;
    const bhalf* Ast = A + (size_t)(m0 + w * 16 + srow) * K + scol;
    const bhalf* Bst = B + (size_t)(n0 + w * 16 + srow) * K + scol;
    const size_t r64K = (size_t)64 * K;

    const int xorr = (r16 & 3) << 4;
    const int rdA = (wm * 64 + r16) * 64 + ((quad * 16) ^ xorr);
    const int rdB = (wn * 64 + r16) * 64 + ((quad * 16) ^ xorr);

    f32x4 acc[4][4];
    #pragma unroll
    for (int i = 0; i < 4; ++i)
        #pragma unroll
        for (int j = 0; j < 4; ++j) acc[i][j] = (f32x4)0.0f;

    const int NT = K >> 5;

    #define STG128(t, buf) do {                                                        \
        gload16(Ast + (size_t)(t) * 32,        (bhalf*)(sA + (buf) * 8192 + w * 1024));        \
        gload16(Ast + (size_t)(t) * 32 + r64K, (bhalf*)(sA + (buf) * 8192 + 4096 + w * 1024)); \
        gload16(Bst + (size_t)(t) * 32,        (bhalf*)(sB + (buf) * 8192 + w * 1024));        \
        gload16(Bst + (size_t)(t) * 32 + r64K, (bhalf*)(sB + (buf) * 8192 + 4096 + w * 1024)); \
    } while (0)

    STG128(0, 0);
    STG128(1, 1);

    int cur = 0, c2 = 2;
    for (int t = 0; t < NT; ++t) {
        if (t + 1 < NT) asm volatile("s_waitcnt vmcnt(4)" ::: "memory");
        else            asm volatile("s_waitcnt vmcnt(0)" ::: "memory");
        __builtin_amdgcn_s_barrier();

        char* const bufA = sA + cur * 8192;
        char* const bufB = sB + cur * 8192;
        bhalf8 af[4], bf[4];
        #pragma unroll
        for (int i = 0; i < 4; ++i) af[i] = *(const bhalf8*)(bufA + rdA + i * 1024);
        #pragma unroll
        for (int j = 0; j < 4; ++j) bf[j] = *(const bhalf8*)(bufB + rdB + j * 1024);

        if (t + 2 < NT) STG128(t + 2, c2);

        __builtin_amdgcn_s_setprio(1);
        #pragma unroll
        for (int i = 0; i < 4; ++i)
            #pragma unroll
            for (int j = 0; j < 4; ++j)
                acc[i][j] = mfma16(af[i], bf[j], acc[i][j]);
        __builtin_amdgcn_s_setprio(0);

        cur = (cur == 2) ? 0 : cur + 1;
        c2 = (c2 == 2) ? 0 : c2 + 1;
    }
    #undef STG128

    #pragma unroll
    for (int i = 0; i < 4; ++i) {
        const int rbase = m0 + wm * 64 + i * 16 + quad * 4;
        #pragma unroll
        for (int rr = 0; rr < 4; ++rr) {
            OutT* crow = C + (size_t)(rbase + rr) * N + n0 + wn * 64 + r16;
            #pragma unroll
            for (int j = 0; j < 4; ++j) crow[j * 16] = (OutT)acc[i][j][rr];
        }
    }
}

// ---------------- fused RoPE q/k (blocks 0..4095) + V transpose ------------
__global__ __launch_bounds__(256) void rope_k(const bhalf* __restrict__ qkv,
                                              const float* __restrict__ freqs,
                                              bhalf* __restrict__ qb,
                                              bhalf* __restrict__ kb,
                                              bhalf* __restrict__ vt) {
    const int blk = blockIdx.x;
    const int tid = threadIdx.x;
    if (blk < BATCH * SEQ) {
        const int b = blk >> 11, s = blk & 2047;
        const bhalf* row = qkv + (size_t)blk * 3072;
        {
            const int h = tid >> 4, d20 = (tid & 15) * 4;
            bhalf8 e = *(const bhalf8*)(row + h * HD + d20 * 2);
            const float* fp = freqs + (size_t)s * 128 + d20 * 2;
            float4 f0 = *(const float4*)fp;
            float4 f1 = *(const float4*)(fp + 4);
            bhalf8 o;
            o[0] = (bhalf)((float)e[0] * f0.x - (float)e[1] * f0.y);
            o[1] = (bhalf)((float)e[0] * f0.y + (float)e[1] * f0.x);
            o[2] = (bhalf)((float)e[2] * f0.z - (float)e[3] * f0.w);
            o[3] = (bhalf)((float)e[2] * f0.w + (float)e[3] * f0.z);
            o[4] = (bhalf)((float)e[4] * f1.x - (float)e[5] * f1.y);
            o[5] = (bhalf)((float)e[4] * f1.y + (float)e[5] * f1.x);
            o[6] = (bhalf)((float)e[6] * f1.z - (float)e[7] * f1.w);
            o[7] = (bhalf)((float)e[6] * f1.w + (float)e[7] * f1.z);
            *(bhalf8*)(qb + ((size_t)(b * N_HEADS + h) * SEQ + s) * HD + d20 * 2) = o;
        }
        if (tid < 64) {
            const int kh = tid >> 4, d20 = (tid & 15) * 4;
            bhalf8 e = *(const bhalf8*)(row + 2048 + kh * HD + d20 * 2);
            const float* fp = freqs + (size_t)s * 128 + d20 * 2;
            float4 f0 = *(const float4*)fp;
            float4 f1 = *(const float4*)(fp + 4);
            bhalf8 o;
            o[0] = (bhalf)((float)e[0] * f0.x - (float)e[1] * f0.y);
            o[1] = (bhalf)((float)e[0] * f0.y + (float)e[1] * f0.x);
            o[2] = (bhalf)((float)e[2] * f0.z - (float)e[3] * f0.w);
            o[3] = (bhalf)((float)e[2] * f0.w + (float)e[3] * f0.z);
            o[4] = (bhalf)((float)e[4] * f1.x - (float)e[5] * f1.y);
            o[5] = (bhalf)((float)e[4] * f1.y + (float)e[5] * f1.x);
            o[6] = (bhalf)((float)e[6] * f1.z - (float)e[7] * f1.w);
            o[7] = (bhalf)((float)e[6] * f1.w + (float)e[7] * f1.z);
            *(bhalf8*)(kb + ((size_t)(b * N_KV + kh) * SEQ + s) * HD + d20 * 2) = o;
        }
    } else {
        const int vb = blk - BATCH * SEQ;
        const int sc = vb & 31;
        const int kvh = (vb >> 5) & 3;
        const int b = vb >> 7;
        const int s0 = sc * 64;
        __shared__ __align__(16) char lds[64 * 256];

        const int rr = tid >> 4;
        const int slot = tid & 15;
        #pragma unroll
        for (int p = 0; p < 4; ++p) {
            const int s = p * 16 + rr;
            bhalf8 v = *(const bhalf8*)(qkv + (size_t)(b * SEQ + s0 + s) * 3072
                                        + 2560 + kvh * HD + slot * 8);
            *(bhalf8*)(lds + s * 256 + ((slot ^ ((s >> 3) & 7)) << 4)) = v;
        }
        __syncthreads();
        const int j = tid & 7;
        const int d0 = tid >> 3;
        #pragma unroll
        for (int p = 0; p < 4; ++p) {
            const int d = p * 32 + d0;
            bhalf8 o;
            #pragma unroll
            for (int e = 0; e < 8; ++e) {
                const int s = j * 8 + e;
                o[e] = *(const bhalf*)(lds + s * 256 + (((d >> 3) ^ j) << 4) + (d & 7) * 2);
            }
            *(bhalf8*)(vt + ((size_t)(b * N_KV + kvh) * HD + d) * SEQ + s0 + j * 8) = o;
        }
    }
}

// ---------------- Flash attention (R2-verified + T5 setprio) ---------------
__global__ __launch_bounds__(256, 2) void attn_k(const bhalf* __restrict__ qb,
                                                 const bhalf* __restrict__ kb,
                                                 const bhalf* __restrict__ vt,
                                                 bhalf* __restrict__ ob) {
    const int tid = threadIdx.x;
    const int wave = tid >> 6, lane = tid & 63;
    const int l31 = lane & 31, h2 = lane >> 5;
    const int qw = wave & 1, kw = wave >> 1;
    const int bid = ((blockIdx.x & 7) << 6) | ((int)blockIdx.x >> 3);
    const int pair = bid & 15;
    const int hh = (bid >> 4) & 15;
    const int b = bid >> 8;
    const int kvh = hh >> 2;

    __shared__ __align__(16) char smem[33792];
    char* const sK = smem;
    char* const sV = smem + 16384;
    float* const mrg = (float*)smem;

    const bhalf* Kbase = kb + (size_t)(b * N_KV + kvh) * SEQ * HD;
    const bhalf* Vbase = vt + (size_t)(b * N_KV + kvh) * HD * SEQ;
    const float SCL2 = 0.08838834764831845f * 1.4426950408889634f;

    const int mbase = (qw * 64 + lane) * 66;
    const int kr = tid >> 4, kce = (tid & 15) * 8;
    const int vr = tid >> 3, vce = (tid & 7) * 8;
    const int kcB = kce * 2, vcB = vce * 2;
    const int Xl = (h2 << 4) ^ ((l31 & 7) << 4);

    for (int phase = 0; phase < 2; ++phase) {
        const int qt = phase ? (31 - pair) : pair;
        const int qrow = qt * 64 + qw * 32 + l31;
        const int qhi = qt * 64 + qw * 32 + 31;

        const bhalf* qbase = qb + (((size_t)(b * N_HEADS + hh) * SEQ) + qrow) * HD;
        bhalf8 qf[8];
        #pragma unroll
        for (int kk = 0; kk < 8; ++kk) {
            bhalf8 q0 = *(const bhalf8*)(qbase + kk * 16 + h2 * 8);
            #pragma unroll
            for (int e = 0; e < 8; ++e) q0[e] = (bhalf)((float)q0[e] * SCL2);
            qf[kk] = q0;
        }

        f32x16 accO[4];
        #pragma unroll
        for (int dt = 0; dt < 4; ++dt) accO[dt] = (f32x16)0.0f;
        float m_i = -1e30f, l_i = 0.0f;

        bhalf8 kreg[4], vreg[4];
        #pragma unroll
        for (int i = 0; i < 4; ++i) {
            kreg[i] = *(const bhalf8*)(Kbase + (size_t)(kr + 16 * i) * HD + kce);
            vreg[i] = *(const bhalf8*)(Vbase + (size_t)(vr + 32 * i) * SEQ + vce);
        }

        for (int kt = 0; kt <= qt; ++kt) {
            __syncthreads();
            #pragma unroll
            for (int i = 0; i < 4; ++i) {
                const int rk = kr + 16 * i;
                *(bhalf8*)(sK + rk * 256 + (kcB ^ ((rk & 7) << 4))) = kreg[i];
                const int rv = vr + 32 * i;
                *(bhalf8*)(sV + rv * 128 + (vcB ^ ((rv & 7) << 4))) = vreg[i];
            }
            __syncthreads();
            if (kt < qt) {
                const int kn = (kt + 1) * 64;
                #pragma unroll
                for (int i = 0; i < 4; ++i) {
                    kreg[i] = *(const bhalf8*)(Kbase + (size_t)(kn + kr + 16 * i) * HD + kce);
                    vreg[i] = *(const bhalf8*)(Vbase + (size_t)(vr + 32 * i) * SEQ + kn + vce);
                }
            }
            if (qhi < kt * 64 + kw * 32) continue;

            f32x16 accS = (f32x16)0.0f;
            const char* kRow = sK + (kw * 32 + l31) * 256;
            __builtin_amdgcn_s_setprio(1);
            #pragma unroll
            for (int kk = 0; kk < 8; ++kk)
                accS = mfma32(*(const bhalf8*)(kRow + ((kk * 32) ^ Xl)), qf[kk], accS);
            __builtin_amdgcn_s_setprio(0);

            if (kt == qt) {
                #pragma unroll
                for (int r = 0; r < 16; ++r) {
                    const int key = kt * 64 + kw * 32 + (r & 3) + 8 * (r >> 2) + 4 * h2;
                    if (key > qrow) accS[r] = -1e30f;
                }
            }

            float mx = -1e30f;
            #pragma unroll
            for (int r = 0; r < 16; ++r) mx = fmaxf(mx, accS[r]);
            mx = fmaxf(mx, __shfl_xor(mx, 32, 64));

            if (!__all(mx <= m_i + 8.0f)) {
                const float mnew = fmaxf(m_i, mx);
                const float alpha = __builtin_amdgcn_exp2f(m_i - mnew);
                m_i = mnew;
                l_i *= alpha;
                #pragma unroll
                for (int dt = 0; dt < 4; ++dt)
                    #pragma unroll
                    for (int r = 0; r < 16; ++r) accO[dt][r] *= alpha;
            }

            float p[16];
            float rs = 0.0f;
            #pragma unroll
            for (int r = 0; r < 16; ++r) {
                p[r] = __builtin_amdgcn_exp2f(accS[r] - m_i);
                rs += p[r];
            }
            rs += __shfl_xor(rs, 32, 64);
            l_i += rs;

            unsigned X0 = cvt_pk_bf16(p[0],  p[1]);
            unsigned X1 = cvt_pk_bf16(p[2],  p[3]);
            unsigned X2 = cvt_pk_bf16(p[4],  p[5]);
            unsigned X3 = cvt_pk_bf16(p[6],  p[7]);
            unsigned X4 = cvt_pk_bf16(p[8],  p[9]);
            unsigned X5 = cvt_pk_bf16(p[10], p[11]);
            unsigned X6 = cvt_pk_bf16(p[12], p[13]);
            unsigned X7 = cvt_pk_bf16(p[14], p[15]);
            plane32_swap(X0, X2);
            plane32_swap(X1, X3);
            plane32_swap(X4, X6);
            plane32_swap(X5, X7);
            union { unsigned u[8]; bhalf8 h[2]; } pk;
            pk.u[0] = X0; pk.u[1] = X1; pk.u[2] = X2; pk.u[3] = X3;
            pk.u[4] = X4; pk.u[5] = X5; pk.u[6] = X6; pk.u[7] = X7;

            __builtin_amdgcn_s_setprio(1);
            #pragma unroll
            for (int kk2 = 0; kk2 < 2; ++kk2) {
                const int cb = (kw << 6) | (kk2 << 5);
                #pragma unroll
                for (int dt = 0; dt < 4; ++dt) {
                    const bhalf8 vfv = *(const bhalf8*)(sV + (dt * 32 + l31) * 128 + (cb ^ Xl));
                    accO[dt] = mfma32(vfv, pk.h[kk2], accO[dt]);
                }
            }
            __builtin_amdgcn_s_setprio(0);
        }

        __syncthreads();
        if (kw == 1) {
            #pragma unroll
            for (int dt = 0; dt < 4; ++dt)
                #pragma unroll
                for (int r = 0; r < 16; ++r) mrg[mbase + dt * 16 + r] = accO[dt][r];
            mrg[mbase + 64] = m_i;
            mrg[mbase + 65] = l_i;
        }
        __syncthreads();
        if (kw == 0) {
            const float m1 = mrg[mbase + 64];
            const float l1 = mrg[mbase + 65];
            const float m = fmaxf(m_i, m1);
            const float b0 = __builtin_amdgcn_exp2f(m_i - m);
            const float b1 = __builtin_amdgcn_exp2f(m1 - m);
            const float inv = 1.0f / (l_i * b0 + l1 * b1);
            bhalf* obase = ob + ((size_t)b * SEQ + qrow) * (size_t)(N_HEADS * HD) + hh * HD;
            #pragma unroll
            for (int dt = 0; dt < 4; ++dt)
                #pragma unroll
                for (int c = 0; c < 4; ++c) {
                    bhalf4 o4;
                    #pragma unroll
                    for (int rr = 0; rr < 4; ++rr) {
                        const float v = accO[dt][c * 4 + rr] * b0 +
                                        mrg[mbase + dt * 16 + c * 4 + rr] * b1;
                        o4[rr] = (bhalf)(v * inv);
                    }
                    *(bhalf4*)(obase + dt * 32 + c * 8 + h2 * 4) = o4;
                }
        }
    }
}

extern "C" void kernel_launch(void* const* d_in, const int* in_sizes, int n_in,
                              void* d_out, int out_size, void* d_ws, size_t ws_size,
                              hipStream_t stream) {
    const float* x      = (const float*)d_in[0];
    const float* freqs  = (const float*)d_in[1];
    const float* norm_w = (const float*)d_in[2];
    const float* wqkv   = (const float*)d_in[3];
    const float* wo     = (const float*)d_in[4];
    float* out = (float*)d_out;

    char* ws = (char*)d_ws;
    bhalf* wqkv_b = (bhalf*)(ws);                      // 12,582,912
    bhalf* wo_b   = (bhalf*)(ws + 12582912);           //  8,388,608
    bhalf* xn     = (bhalf*)(ws + 20971520);           // 16,777,216
    bhalf* qkv    = (bhalf*)(ws + 37748736);           // 25,165,824 (bf16)
    bhalf* qb     = (bhalf*)(ws + 88080384);           // 16,777,216
    bhalf* kb     = (bhalf*)(ws + 104857600);          //  4,194,304
    bhalf* vtb    = (bhalf*)(ws + 109051904);          //  4,194,304
    bhalf* attn   = (bhalf*)(ws + 113246208);          // 16,777,216

    static bool attr_done = false;
    if (!attr_done) {
        hipFuncSetAttribute((const void*)gemmq,
                            hipFuncAttributeMaxDynamicSharedMemorySize, 114688);
        attr_done = true;
    }

    prep_k<<<BATCH * SEQ + 10240, 256, 0, stream>>>(x, norm_w, xn, wqkv, wo, wqkv_b);
    gemmq<<<256, 512, 114688, stream>>>(xn, wqkv_b, qkv, 3072, 2048);
    rope_k<<<BATCH * SEQ + 256, 256, 0, stream>>>(qkv, freqs, qb, kb, vtb);
    attn_k<<<512, 256, 0, stream>>>(qb, kb, vtb, attn);
    gemm128<float><<<512, 256, 0, stream>>>(attn, wo_b, out, 2048, 2048);
}